// Round 16
// baseline (157.288 us; speedup 1.0000x reference)
//
#include <hip/hip_runtime.h>
#include <hip/hip_bf16.h>

using bf16 = __hip_bfloat16;

typedef __attribute__((ext_vector_type(8))) short short8;   // 8 x bf16 (4 VGPR)
typedef __attribute__((ext_vector_type(4))) float f32x4;

#define DEVI __device__ __forceinline__

DEVI float u2f(unsigned short u) {
    union { unsigned int i; float f; } c;
    c.i = ((unsigned int)u) << 16;
    return c.f;
}

DEVI unsigned short f2u(float f) {
    union { float f; unsigned int i; } c;
    c.f = f;
    unsigned int x = c.i;
    unsigned int lsb = (x >> 16) & 1u;
    x += 0x7fffu + lsb;            // round-to-nearest-even
    return (unsigned short)(x >> 16);
}

DEVI float gelu_f(float x) {
    const float kA = 0.7978845608028654f;  // sqrt(2/pi)
    float inner = kA * (x + 0.044715f * x * x * x);
    return 0.5f * x * (1.0f + tanhf(inner));
}

DEVI void gload16(const void* g, void* l) {
    __builtin_amdgcn_global_load_lds(
        (const __attribute__((address_space(1))) void*)g,
        (__attribute__((address_space(3))) void*)l, 16, 0, 0);
}

// ---------------- fused prep: weight transpose-convert + LN1 ----------------
// 1D grid, 6144 blocks x 256 thr:
//   bid <  1024 : wconv z = bid>>8 (Wq x0.125, Wk, Wv, Wo), 16x16 tiles
//   bid <  1536 : wconv W1 (16 kt x 32 nt)
//   bid <  2048 : wconv W2 (32 kt x 16 nt)
//   bid >= 2048 : LN1, 2 rows per block (threads [0,128) and [128,256))
__global__ __launch_bounds__(256) void prep_kernel(
    const float* __restrict__ Wq, const float* __restrict__ Wk,
    const float* __restrict__ Wv, const float* __restrict__ Wo,
    const float* __restrict__ W1, const float* __restrict__ W2,
    bf16* __restrict__ WqkvT, bf16* __restrict__ WoT,
    bf16* __restrict__ W1T, bf16* __restrict__ W2T,
    const float* __restrict__ inp, const float* __restrict__ ln1s,
    const float* __restrict__ ln1b, bf16* __restrict__ xb)
{
    __shared__ float t[32][33];
    __shared__ float red[4];
    const int bid = blockIdx.x;

    if (bid < 2048) {
        int z, xt, yt;
        if (bid < 1024)      { z = bid >> 8; const int i = bid & 255;  xt = i >> 4; yt = i & 15; }
        else if (bid < 1536) { z = 4;        const int i = bid - 1024; xt = i >> 5; yt = i & 31; }
        else                 { z = 5;        const int i = bid - 1536; xt = i >> 4; yt = i & 15; }
        const float* W; bf16* WT; int K, N; float scale = 1.0f;
        switch (z) {
            case 0: W = Wq; WT = WqkvT;              K = 512;  N = 512;  scale = 0.125f; break;
            case 1: W = Wk; WT = WqkvT + 512 * 512;  K = 512;  N = 512;  break;
            case 2: W = Wv; WT = WqkvT + 1024 * 512; K = 512;  N = 512;  break;
            case 3: W = Wo; WT = WoT;                K = 512;  N = 512;  break;
            case 4: W = W1; WT = W1T;                K = 512;  N = 1024; break;
            default: W = W2; WT = W2T;               K = 1024; N = 512;  break;
        }
        const int kt = xt * 32, nt = yt * 32;
        const int tx = threadIdx.x & 31, ty = threadIdx.x >> 5;   // 32 x 8
#pragma unroll
        for (int p = 0; p < 4; ++p)
            t[ty + p * 8][tx] = W[(size_t)(kt + ty + p * 8) * N + nt + tx];
        __syncthreads();
#pragma unroll
        for (int p = 0; p < 4; ++p)
            ((unsigned short*)WT)[(size_t)(nt + ty + p * 8) * K + kt + tx] =
                f2u(t[tx][ty + p * 8] * scale);
        return;
    }

    // ---- LN1: 2 rows per block ----
    const int row = (bid - 2048) * 2 + (threadIdx.x >> 7);
    const int tl = threadIdx.x & 127;
    const int rb = (threadIdx.x >> 7) * 2;          // red base for this row
    const float4 r4 = ((const float4*)(inp + (size_t)row * 512))[tl];
    float v[4] = { r4.x, r4.y, r4.z, r4.w };

    float s = v[0] + v[1] + v[2] + v[3];
#pragma unroll
    for (int off = 32; off; off >>= 1) s += __shfl_xor(s, off);
    if ((threadIdx.x & 63) == 0) red[threadIdx.x >> 6] = s;
    __syncthreads();
    const float mean = (red[rb] + red[rb + 1]) * (1.0f / 512.0f);

    float c[4];
    float sq = 0.f;
#pragma unroll
    for (int i = 0; i < 4; ++i) { c[i] = v[i] - mean; sq += c[i] * c[i]; }
#pragma unroll
    for (int off = 32; off; off >>= 1) sq += __shfl_xor(sq, off);
    __syncthreads();
    if ((threadIdx.x & 63) == 0) red[threadIdx.x >> 6] = sq;
    __syncthreads();
    const float var = (red[rb] + red[rb + 1]) * (1.0f / 512.0f);
    const float rs = rsqrtf(var + 1e-6f);

    const float4 g4 = ((const float4*)ln1s)[tl];
    const float4 b4 = ((const float4*)ln1b)[tl];
    ushort4 o4;
    o4.x = f2u(c[0] * rs * g4.x + b4.x);
    o4.y = f2u(c[1] * rs * g4.y + b4.y);
    o4.z = f2u(c[2] * rs * g4.z + b4.z);
    o4.w = f2u(c[3] * rs * g4.w + b4.w);
    ((ushort4*)(xb + (size_t)row * 512))[tl] = o4;
}

// ---------------- LayerNorm: one row (D=512) per block, 128 thr x 4 elem ----
__global__ __launch_bounds__(128) void ln_kernel(
    const float* __restrict__ in, const float* __restrict__ gamma,
    const float* __restrict__ beta, bf16* __restrict__ out)
{
    const int row = blockIdx.x;
    const int t = threadIdx.x;
    const float4 r4 = ((const float4*)(in + (size_t)row * 512))[t];
    float v[4] = { r4.x, r4.y, r4.z, r4.w };

    __shared__ float red[2];
    float s = v[0] + v[1] + v[2] + v[3];
#pragma unroll
    for (int off = 32; off; off >>= 1) s += __shfl_xor(s, off);
    if ((t & 63) == 0) red[t >> 6] = s;
    __syncthreads();
    const float mean = (red[0] + red[1]) * (1.0f / 512.0f);

    float c[4];
    float sq = 0.f;
#pragma unroll
    for (int i = 0; i < 4; ++i) { c[i] = v[i] - mean; sq += c[i] * c[i]; }
#pragma unroll
    for (int off = 32; off; off >>= 1) sq += __shfl_xor(sq, off);
    __syncthreads();
    if ((t & 63) == 0) red[t >> 6] = sq;
    __syncthreads();
    const float var = (red[0] + red[1]) * (1.0f / 512.0f);
    const float rs = rsqrtf(var + 1e-6f);

    const float4 g4 = ((const float4*)gamma)[t];
    const float4 b4 = ((const float4*)beta)[t];
    ushort4 o4;
    o4.x = f2u(c[0] * rs * g4.x + b4.x);
    o4.y = f2u(c[1] * rs * g4.y + b4.y);
    o4.z = f2u(c[2] * rs * g4.z + b4.z);
    o4.w = f2u(c[3] * rs * g4.w + b4.w);
    ((ushort4*)(out + (size_t)row * 512))[t] = o4;
}

// ---------------- MFMA GEMM: C = act((A@BT^T) + bias) + res ----------------
// A [M][lda>=K] bf16, BT [N][K] bf16 (pre-transposed weights).
// Tile 128(M) x 64(N), templated BK, single-buffer 2-barrier structure.
// BK=128 only for grid-limited GEMMs (<=2 blocks/CU): LDS 48 KB still allows
// 3/CU, and K-step barrier-drain count halves. 1D grid, XCD-swizzled (T1).
// VSPLIT: blocks with colBase >= 1024 write transposed V to vt.
template<int ACT, int VSPLIT, int BK, typename TO>  // ACT: 0 = none, 1 = gelu
__global__ __launch_bounds__(256) void mfma_gemm(
    const bf16* __restrict__ A, int lda, const bf16* __restrict__ BT,
    const float* __restrict__ bias, const float* __restrict__ res,
    TO* __restrict__ C, int ldc, int K, bf16* __restrict__ vt, int NX)
{
    __shared__ __attribute__((aligned(16))) bf16 a_lds[128 * BK];
    __shared__ __attribute__((aligned(16))) bf16 b_lds[64 * BK];

    const int bid = blockIdx.x;
    const int xcd = bid & 7;
    const int k = bid >> 3;
    const int ypg = (int)(gridDim.x >> 3) / NX;   // row-panels per XCD
    const int yb = xcd * ypg + k / NX;
    const int xb = k % NX;

    const int tid = threadIdx.x;
    const int w = tid >> 6, lane = tid & 63;
    const int cl = lane & 15, g = lane >> 4;
    const int wr = w >> 1, wc = w & 1;
    const int rowBase = yb * 128;
    const int colBase = xb * 64;
    constexpr int TPR = BK / 8;         // threads per staged row
    constexpr int RPR = 256 / TPR;      // rows staged per issue-round
    const int lr = tid / TPR;
    const int lc = (tid % TPR) << 3;

    f32x4 acc[4][2] = {};

    for (int k0 = 0; k0 < K; k0 += BK) {
        __syncthreads();
#pragma unroll
        for (int i = 0; i < 128 / RPR; ++i)
            gload16(A + (size_t)(rowBase + i * RPR + lr) * lda + k0 + lc,
                    &a_lds[(i * RPR + lr) * BK + lc]);
#pragma unroll
        for (int i = 0; i < 64 / RPR; ++i)
            gload16(BT + (size_t)(colBase + i * RPR + lr) * K + k0 + lc,
                    &b_lds[(i * RPR + lr) * BK + lc]);
        __syncthreads();

#pragma unroll
        for (int ks = 0; ks < BK / 32; ++ks) {
            short8 af[4], bfr[2];
#pragma unroll
            for (int mi = 0; mi < 4; ++mi)
                af[mi] = *(const short8*)&a_lds[(wr * 64 + mi * 16 + cl) * BK + ks * 32 + g * 8];
#pragma unroll
            for (int ni = 0; ni < 2; ++ni)
                bfr[ni] = *(const short8*)&b_lds[(wc * 32 + ni * 16 + cl) * BK + ks * 32 + g * 8];
#pragma unroll
            for (int mi = 0; mi < 4; ++mi)
#pragma unroll
                for (int ni = 0; ni < 2; ++ni)
                    acc[mi][ni] = __builtin_amdgcn_mfma_f32_16x16x32_bf16(
                        af[mi], bfr[ni], acc[mi][ni], 0, 0, 0);
        }
    }

    if (VSPLIT && colBase >= 1024) {
        // V range: write transposed, 4 consecutive rows -> one 8B store
#pragma unroll
        for (int mi = 0; mi < 4; ++mi) {
#pragma unroll
            for (int ni = 0; ni < 2; ++ni) {
                const int row0 = rowBase + wr * 64 + mi * 16 + g * 4;
                const int vcol = colBase + wc * 32 + ni * 16 + cl - 1024;
                const int bb = row0 >> 10, pos = row0 & 1023;
                const int h = vcol >> 6, d = vcol & 63;
                ushort4 o4 = { f2u(acc[mi][ni][0]), f2u(acc[mi][ni][1]),
                               f2u(acc[mi][ni][2]), f2u(acc[mi][ni][3]) };
                *(ushort4*)(vt + ((size_t)((bb * 8 + h) * 64 + d) << 10) + pos) = o4;
            }
        }
        return;
    }

#pragma unroll
    for (int mi = 0; mi < 4; ++mi) {
#pragma unroll
        for (int ni = 0; ni < 2; ++ni) {
            const int row0 = rowBase + wr * 64 + mi * 16 + g * 4;
            const int col = colBase + wc * 32 + ni * 16 + cl;
            const float bv = bias ? bias[col] : 0.0f;
#pragma unroll
            for (int j = 0; j < 4; ++j) {
                float vv = acc[mi][ni][j] + bv;
                if (ACT == 1) vv = gelu_f(vv);
                if (res) vv += res[(size_t)(row0 + j) * ldc + col];
                if constexpr (sizeof(TO) == 2)
                    ((unsigned short*)C)[(size_t)(row0 + j) * ldc + col] = f2u(vv);
                else
                    ((float*)C)[(size_t)(row0 + j) * ldc + col] = vv;
            }
        }
    }
}

// ---------------- BigBird attention (XCD swizzle + global-block key-split) --
// qk layout [B*L][1024]: q cols 0-511, k cols 512-1023. vt layout
// [(b*8+h)*64 + d][1024 pos]. O written in-place over q columns (middle
// blocks) or to o_part/lp_part scratch (m=0/15, split into two 8-tile
// halves along the key axis -- no-max softmax partials combine linearly;
// attn_combine merges them). 18 slots per (b,h): 0,1 = m=0 parts; 2,3 =
// m=15 parts; 4..17 = m=1..14. All slots of one (b,h) land on one XCD.
__global__ __launch_bounds__(256) void attn_kernel(
    bf16* qk, const bf16* __restrict__ vt, const int* __restrict__ rnd,
    bf16* __restrict__ o_part, float* __restrict__ lp_part)
{
    const int bid = blockIdx.x;
    const int xcd = bid & 7, kkk = bid >> 3;      // kkk in [0,144)
    const int bhg = kkk / 18, slot = kkk % 18;
    const int bh_idx = bhg * 8 + xcd;             // [0,64): b*8+h
    const int b = bh_idx >> 3, h = bh_idx & 7;
    const bool partial = slot < 4;
    const int m = partial ? ((slot < 2) ? 0 : 15) : (slot - 3);
    const int LD = 1024;

    __shared__ __attribute__((aligned(16))) unsigned short k_lds[64][72];  // [key][d]
    __shared__ __attribute__((aligned(16))) unsigned short vt_lds[64][72]; // [d][key]
    __shared__ __attribute__((aligned(16))) unsigned short p_lds[64][72];  // [q][key] (wave-private rows)
    __shared__ int sh_idx[16];
    __shared__ int sh_n;

    const int tid = threadIdx.x;
    if (tid == 0) {
        int tmp[16]; int cnt = 0;
        if (partial) {
            const int base = (slot & 1) * 8;
            for (int s = 0; s < 8; ++s) tmp[cnt++] = base + s;
        } else {
            const int cand[8] = { 0, 15, m - 1, m, m + 1,
                                  rnd[m * 3], rnd[m * 3 + 1], rnd[m * 3 + 2] };
            for (int s = 0; s < 8; ++s) {
                bool dup = false;
                for (int t2 = 0; t2 < cnt; ++t2) dup = dup || (tmp[t2] == cand[s]);
                if (!dup) tmp[cnt++] = cand[s];
            }
        }
        sh_n = cnt;
        for (int s = 0; s < cnt; ++s) sh_idx[s] = tmp[s];
    }

    const int w = tid >> 6, lane = tid & 63;
    const int cl = lane & 15;          // "column" lane index
    const int g  = lane >> 4;          // k-group / row-group index
    const size_t bh = (size_t)b * 1024;

    short8 qa0, qa1;
    {
        const bf16* qp = qk + (bh + m * 64 + w * 16 + cl) * LD + h * 64 + g * 8;
        qa0 = *(const short8*)(qp);
        qa1 = *(const short8*)(qp + 32);
    }

    f32x4 o_acc[4] = {};
    f32x4 lp = {};                      // per-lane partial denominator

    const int srow = tid >> 2, sseg = (tid & 3) << 4;   // staging map (K and V)
    const bf16* kbase = qk + 512 + h * 64;
    const bf16* vbase = vt + ((size_t)((b * 8 + h) * 64 + srow) << 10) + sseg;

    __syncthreads();                      // sh_idx ready; all Q reads done
    const int S = sh_n;

    // prefetch tile 0
    short8 kp0, kp1, vp0, vp1;
    {
        const int kb = sh_idx[0];
        const short8* ks8 = (const short8*)(kbase + (bh + kb * 64 + srow) * LD + sseg);
        kp0 = ks8[0]; kp1 = ks8[1];
        const short8* vs8 = (const short8*)(vbase + kb * 64);
        vp0 = vs8[0]; vp1 = vs8[1];
    }

    for (int s = 0; s < S; ++s) {
        // ---- write prefetched K/V regs to LDS (row-major, b128 each) ----
        *(short8*)&k_lds[srow][sseg] = kp0;
        *(short8*)&k_lds[srow][sseg + 8] = kp1;
        *(short8*)&vt_lds[srow][sseg] = vp0;
        *(short8*)&vt_lds[srow][sseg + 8] = vp1;
        __syncthreads();                  // barrier A: stage visible

        // ---- issue next tile's global loads (hidden under compute) ----
        if (s + 1 < S) {
            const int kb = sh_idx[s + 1];
            const short8* ks8 = (const short8*)(kbase + (bh + kb * 64 + srow) * LD + sseg);
            kp0 = ks8[0]; kp1 = ks8[1];
            const short8* vs8 = (const short8*)(vbase + kb * 64);
            vp0 = vs8[0]; vp1 = vs8[1];
        }

        // ---- QK^T: 4 key-tiles x 2 d-steps ----
        f32x4 sc[4];
        __builtin_amdgcn_s_setprio(1);
#pragma unroll
        for (int nt = 0; nt < 4; ++nt) {
            const short8 kb0 = *(const short8*)&k_lds[nt * 16 + cl][g * 8];
            const short8 kb1 = *(const short8*)&k_lds[nt * 16 + cl][32 + g * 8];
            f32x4 acc = {};
            acc = __builtin_amdgcn_mfma_f32_16x16x32_bf16(qa0, kb0, acc, 0, 0, 0);
            acc = __builtin_amdgcn_mfma_f32_16x16x32_bf16(qa1, kb1, acc, 0, 0, 0);
            sc[nt] = acc;
        }
        __builtin_amdgcn_s_setprio(0);

        // ---- p = exp(score), accumulate denominator partials ----
        f32x4 p[4];
#pragma unroll
        for (int nt = 0; nt < 4; ++nt) {
            p[nt].x = __expf(sc[nt].x);
            p[nt].y = __expf(sc[nt].y);
            p[nt].z = __expf(sc[nt].z);
            p[nt].w = __expf(sc[nt].w);
        }
        lp += p[0] + p[1] + p[2] + p[3];

        // ---- P -> bf16 -> LDS (wave-private rows; lgkm-ordered) ----
        {
            const int pr = w * 16 + g * 4;
#pragma unroll
            for (int nt = 0; nt < 4; ++nt) {
                p_lds[pr + 0][nt * 16 + cl] = f2u(p[nt].x);
                p_lds[pr + 1][nt * 16 + cl] = f2u(p[nt].y);
                p_lds[pr + 2][nt * 16 + cl] = f2u(p[nt].z);
                p_lds[pr + 3][nt * 16 + cl] = f2u(p[nt].w);
            }
        }

        // ---- PV: O += P @ V ----
        {
            const short8 pa0 = *(const short8*)&p_lds[w * 16 + cl][g * 8];
            const short8 pa1 = *(const short8*)&p_lds[w * 16 + cl][32 + g * 8];
            __builtin_amdgcn_s_setprio(1);
#pragma unroll
            for (int nt = 0; nt < 4; ++nt) {
                const short8 vb0 = *(const short8*)&vt_lds[nt * 16 + cl][g * 8];
                const short8 vb1 = *(const short8*)&vt_lds[nt * 16 + cl][32 + g * 8];
                o_acc[nt] = __builtin_amdgcn_mfma_f32_16x16x32_bf16(pa0, vb0, o_acc[nt], 0, 0, 0);
                o_acc[nt] = __builtin_amdgcn_mfma_f32_16x16x32_bf16(pa1, vb1, o_acc[nt], 0, 0, 0);
            }
            __builtin_amdgcn_s_setprio(0);
        }
        __syncthreads();       // barrier C: PV/QK reads done before next stage
    }

    // ---- reduce denominator over the 16 cl lanes ----
#pragma unroll
    for (int mask = 1; mask <= 8; mask <<= 1) {
        lp.x += __shfl_xor(lp.x, mask);
        lp.y += __shfl_xor(lp.y, mask);
        lp.z += __shfl_xor(lp.z, mask);
        lp.w += __shfl_xor(lp.w, mask);
    }

    if (partial) {
        // unnormalized partial -> scratch (bf16 o, f32 lp)
        const int ps = bh_idx * 4 + slot;
        unsigned short* op = (unsigned short*)o_part
            + ((size_t)ps * 64 + w * 16 + g * 4) * 64 + cl;
#pragma unroll
        for (int nt = 0; nt < 4; ++nt) {
            op[nt * 16 + 0 * 64] = f2u(o_acc[nt].x);
            op[nt * 16 + 1 * 64] = f2u(o_acc[nt].y);
            op[nt * 16 + 2 * 64] = f2u(o_acc[nt].z);
            op[nt * 16 + 3 * 64] = f2u(o_acc[nt].w);
        }
        if (cl == 0) {
            float* lpp = lp_part + ps * 64 + w * 16 + g * 4;
            lpp[0] = lp.x; lpp[1] = lp.y; lpp[2] = lp.z; lpp[3] = lp.w;
        }
        return;
    }

    f32x4 inv;
    inv.x = 1.0f / lp.x; inv.y = 1.0f / lp.y;
    inv.z = 1.0f / lp.z; inv.w = 1.0f / lp.w;
    const size_t orow = bh + m * 64 + w * 16 + g * 4;
    bf16* ob = qk + orow * LD + h * 64 + cl;
#pragma unroll
    for (int nt = 0; nt < 4; ++nt) {
        const f32x4 ov = o_acc[nt] * inv;
        ((unsigned short*)(ob))[nt * 16] = f2u(ov.x);
        ((unsigned short*)(ob + LD))[nt * 16] = f2u(ov.y);
        ((unsigned short*)(ob + 2 * LD))[nt * 16] = f2u(ov.z);
        ((unsigned short*)(ob + 3 * LD))[nt * 16] = f2u(ov.w);
    }
}

// ---------------- combine the split global-block partials --------------------
// grid (64, 2): (bh_idx, which m: 0->m=0, 1->m=15). 256 thr: q = t>>2,
// 16 d per thread. O = (o0 + o1) / (l0 + l1), write bf16 into qk q-cols.
__global__ __launch_bounds__(256) void attn_combine(
    const bf16* __restrict__ o_part, const float* __restrict__ lp_part,
    bf16* __restrict__ qk)
{
    const int bh_idx = blockIdx.x;
    const int which = blockIdx.y;
    const int b = bh_idx >> 3, h = bh_idx & 7;
    const int m = which ? 15 : 0;
    const int s0 = bh_idx * 4 + which * 2;
    const int t = threadIdx.x;
    const int q = t >> 2, d0 = (t & 3) << 4;

    const float l = lp_part[s0 * 64 + q] + lp_part[(s0 + 1) * 64 + q];
    const float inv = 1.0f / l;
    const bf16* p0 = o_part + ((size_t)s0 * 64 + q) * 64 + d0;
    const bf16* p1 = o_part + ((size_t)(s0 + 1) * 64 + q) * 64 + d0;
    bf16* dst = qk + ((size_t)(b * 1024 + m * 64 + q)) * 1024 + h * 64 + d0;

    const short8 a0 = *(const short8*)p0, a1 = *(const short8*)(p0 + 8);
    const short8 b0 = *(const short8*)p1, b1 = *(const short8*)(p1 + 8);
    short8 r0, r1;
#pragma unroll
    for (int i = 0; i < 8; ++i) {
        r0[i] = (short)f2u((u2f((unsigned short)a0[i]) + u2f((unsigned short)b0[i])) * inv);
        r1[i] = (short)f2u((u2f((unsigned short)a1[i]) + u2f((unsigned short)b1[i])) * inv);
    }
    *(short8*)dst = r0;
    *(short8*)(dst + 8) = r1;
}

// ---------------------------------------------------------------------------
extern "C" void kernel_launch(void* const* d_in, const int* in_sizes, int n_in,
                              void* d_out, int out_size, void* d_ws, size_t ws_size,
                              hipStream_t stream)
{
    (void)in_sizes; (void)n_in; (void)out_size; (void)ws_size;
    const float* inp  = (const float*)d_in[0];
    const float* ln1s = (const float*)d_in[2];
    const float* ln1b = (const float*)d_in[3];
    const float* Wq   = (const float*)d_in[4];
    const float* Wk   = (const float*)d_in[5];
    const float* Wv   = (const float*)d_in[6];
    const float* Wo   = (const float*)d_in[7];
    const float* ln2s = (const float*)d_in[8];
    const float* ln2b = (const float*)d_in[9];
    const float* W1   = (const float*)d_in[10];
    const float* b1   = (const float*)d_in[11];
    const float* W2   = (const float*)d_in[12];
    const float* b2   = (const float*)d_in[13];
    const int*  rnd   = (const int*)d_in[14];
    float* out = (float*)d_out;

    char* ws = (char*)d_ws;
    const size_t MB = 1024 * 1024;
    bf16* WqkvT  = (bf16*)(ws);            // 1.5 MB: [1536][512]
    bf16* WoT    = (bf16*)(ws + 2 * MB);   // 0.5 MB
    bf16* W1T    = (bf16*)(ws + 3 * MB);   // 1 MB: [1024][512]
    bf16* W2T    = (bf16*)(ws + 4 * MB);   // 1 MB: [512][1024]
    bf16* o_part = (bf16*)(ws + 5 * MB);   // 2 MB: [64*4][64][64]
    float* lp_part = (float*)(ws + 7 * MB);// 64 KB: [64*4][64]
    bf16* qk     = (bf16*)(ws + 8 * MB);   // 16 MB: [8192][1024] (q | k)
    bf16* vtb    = (bf16*)(ws + 24 * MB);  // 8 MB: [4096][1024] (V^T per b,h)
    bf16* y      = (bf16*)(ws + 8 * MB);   // alias qk (dead after Wo): LN2 out
    bf16* h1     = (bf16*)(ws + 16 * MB);  // 16 MB: MLP hidden
    bf16* xb     = (bf16*)d_out;           // LN1 out; d_out scratch until Wo GEMM

    prep_kernel<<<6144, 256, 0, stream>>>(Wq, Wk, Wv, Wo, W1, W2,
                                          WqkvT, WoT, W1T, W2T,
                                          inp, ln1s, ln1b, xb);
    mfma_gemm<0, 1, 64, bf16><<<1536, 256, 0, stream>>>(xb, 512, WqkvT, nullptr, nullptr, qk, 1024, 512, vtb, 24);
    attn_kernel<<<1152, 256, 0, stream>>>(qk, vtb, rnd, o_part, lp_part);
    attn_combine<<<dim3(64, 2), 256, 0, stream>>>(o_part, lp_part, qk);
    mfma_gemm<0, 0, 128, float><<<512, 256, 0, stream>>>(qk, 1024, WoT, nullptr, inp, out, 512, 512, nullptr, 8);
    ln_kernel<<<8192, 128, 0, stream>>>(out, ln2s, ln2b, y);
    mfma_gemm<1, 0, 64, bf16><<<1024, 256, 0, stream>>>(y, 512, W1T, b1, nullptr, h1, 1024, 512, nullptr, 16);
    mfma_gemm<0, 0, 128, float><<<512, 256, 0, stream>>>(h1, 1024, W2T, b2, out, out, 512, 1024, nullptr, 8);
}

// Round 17
// 151.335 us; speedup vs baseline: 1.0393x; 1.0393x over previous
//
#include <hip/hip_runtime.h>
#include <hip/hip_bf16.h>

using bf16 = __hip_bfloat16;

typedef __attribute__((ext_vector_type(8))) short short8;   // 8 x bf16 (4 VGPR)
typedef __attribute__((ext_vector_type(4))) float f32x4;

#define DEVI __device__ __forceinline__

DEVI float u2f(unsigned short u) {
    union { unsigned int i; float f; } c;
    c.i = ((unsigned int)u) << 16;
    return c.f;
}

DEVI unsigned short f2u(float f) {
    union { float f; unsigned int i; } c;
    c.f = f;
    unsigned int x = c.i;
    unsigned int lsb = (x >> 16) & 1u;
    x += 0x7fffu + lsb;            // round-to-nearest-even
    return (unsigned short)(x >> 16);
}

DEVI float gelu_f(float x) {
    const float kA = 0.7978845608028654f;  // sqrt(2/pi)
    float inner = kA * (x + 0.044715f * x * x * x);
    return 0.5f * x * (1.0f + tanhf(inner));
}

DEVI void gload16(const void* g, void* l) {
    __builtin_amdgcn_global_load_lds(
        (const __attribute__((address_space(1))) void*)g,
        (__attribute__((address_space(3))) void*)l, 16, 0, 0);
}

// ---------------- merged weight transpose-convert ---------------------------
// z: 0..5 -> {Wq(x0.125),Wk,Wv -> WqkvT rows 0/512/1024}, Wo, W1, W2.
__global__ __launch_bounds__(256) void wconv_all(
    const float* __restrict__ Wq, const float* __restrict__ Wk,
    const float* __restrict__ Wv, const float* __restrict__ Wo,
    const float* __restrict__ W1, const float* __restrict__ W2,
    bf16* __restrict__ WqkvT, bf16* __restrict__ WoT,
    bf16* __restrict__ W1T, bf16* __restrict__ W2T)
{
    const int z = blockIdx.z;
    const float* W; bf16* WT; int K, N; float scale = 1.0f;
    switch (z) {
        case 0: W = Wq; WT = WqkvT;              K = 512;  N = 512;  scale = 0.125f; break;
        case 1: W = Wk; WT = WqkvT + 512 * 512;  K = 512;  N = 512;  break;
        case 2: W = Wv; WT = WqkvT + 1024 * 512; K = 512;  N = 512;  break;
        case 3: W = Wo; WT = WoT;                K = 512;  N = 512;  break;
        case 4: W = W1; WT = W1T;                K = 512;  N = 1024; break;
        default: W = W2; WT = W2T;               K = 1024; N = 512;  break;
    }
    const int kt = blockIdx.x * 32, nt = blockIdx.y * 32;
    if (kt >= K || nt >= N) return;

    __shared__ float t[32][33];
    const int tx = threadIdx.x & 31, ty = threadIdx.x >> 5;   // 32 x 8
#pragma unroll
    for (int p = 0; p < 4; ++p)
        t[ty + p * 8][tx] = W[(size_t)(kt + ty + p * 8) * N + nt + tx];
    __syncthreads();
#pragma unroll
    for (int p = 0; p < 4; ++p)
        ((unsigned short*)WT)[(size_t)(nt + ty + p * 8) * K + kt + tx] =
            f2u(t[tx][ty + p * 8] * scale);
}

// ---------------- LayerNorm: one row (D=512) per block, 128 thr x 4 elem ----
__global__ __launch_bounds__(128) void ln_kernel(
    const float* __restrict__ in, const float* __restrict__ gamma,
    const float* __restrict__ beta, bf16* __restrict__ out)
{
    const int row = blockIdx.x;
    const int t = threadIdx.x;
    const float4 r4 = ((const float4*)(in + (size_t)row * 512))[t];
    float v[4] = { r4.x, r4.y, r4.z, r4.w };

    __shared__ float red[2];
    float s = v[0] + v[1] + v[2] + v[3];
#pragma unroll
    for (int off = 32; off; off >>= 1) s += __shfl_xor(s, off);
    if ((t & 63) == 0) red[t >> 6] = s;
    __syncthreads();
    const float mean = (red[0] + red[1]) * (1.0f / 512.0f);

    float c[4];
    float sq = 0.f;
#pragma unroll
    for (int i = 0; i < 4; ++i) { c[i] = v[i] - mean; sq += c[i] * c[i]; }
#pragma unroll
    for (int off = 32; off; off >>= 1) sq += __shfl_xor(sq, off);
    __syncthreads();
    if ((t & 63) == 0) red[t >> 6] = sq;
    __syncthreads();
    const float var = (red[0] + red[1]) * (1.0f / 512.0f);
    const float rs = rsqrtf(var + 1e-6f);

    const float4 g4 = ((const float4*)gamma)[t];
    const float4 b4 = ((const float4*)beta)[t];
    ushort4 o4;
    o4.x = f2u(c[0] * rs * g4.x + b4.x);
    o4.y = f2u(c[1] * rs * g4.y + b4.y);
    o4.z = f2u(c[2] * rs * g4.z + b4.z);
    o4.w = f2u(c[3] * rs * g4.w + b4.w);
    ((ushort4*)(out + (size_t)row * 512))[t] = o4;
}

// ---------------- MFMA GEMM: C = act((A@BT^T) + bias) + res ----------------
// A [M][lda>=K] bf16, BT [N][K] bf16 (pre-transposed weights).
// Tile 128(M) x 64(N), BK=64, single-buffer (round-7 proven structure).
// 1D grid, XCD-swizzled (T1): each XCD owns NY/8 row-panels x ALL col-tiles,
// so a 128-row A-panel is fetched into exactly one XCD's L2 and reused by
// all NX col-blocks (instead of 8 XCDs each fetching a copy).
// VSPLIT: blocks with colBase >= 1024 write transposed V to vt.
template<int ACT, int VSPLIT, typename TO>  // ACT: 0 = none, 1 = gelu
__global__ __launch_bounds__(256) void mfma_gemm(
    const bf16* __restrict__ A, int lda, const bf16* __restrict__ BT,
    const float* __restrict__ bias, const float* __restrict__ res,
    TO* __restrict__ C, int ldc, int K, bf16* __restrict__ vt, int NX)
{
    __shared__ __attribute__((aligned(16))) bf16 a_lds[128 * 64];
    __shared__ __attribute__((aligned(16))) bf16 b_lds[64 * 64];

    const int bid = blockIdx.x;
    const int xcd = bid & 7;
    const int k = bid >> 3;
    const int ypg = (int)(gridDim.x >> 3) / NX;   // row-panels per XCD
    const int yb = xcd * ypg + k / NX;
    const int xb = k % NX;

    const int tid = threadIdx.x;
    const int w = tid >> 6, lane = tid & 63;
    const int cl = lane & 15, g = lane >> 4;
    const int wr = w >> 1, wc = w & 1;
    const int rowBase = yb * 128;
    const int colBase = xb * 64;
    const int lr = tid >> 3;            // 0..31: staging row within issue
    const int lc = (tid & 7) << 3;      // staging col (elems): 0,8,...,56

    f32x4 acc[4][2] = {};

    for (int k0 = 0; k0 < K; k0 += 64) {
        __syncthreads();
#pragma unroll
        for (int i = 0; i < 4; ++i)
            gload16(A + (size_t)(rowBase + i * 32 + lr) * lda + k0 + lc,
                    &a_lds[(i * 32 + lr) * 64 + lc]);
#pragma unroll
        for (int i = 0; i < 2; ++i)
            gload16(BT + (size_t)(colBase + i * 32 + lr) * K + k0 + lc,
                    &b_lds[(i * 32 + lr) * 64 + lc]);
        __syncthreads();

#pragma unroll
        for (int ks = 0; ks < 2; ++ks) {
            short8 af[4], bfr[2];
#pragma unroll
            for (int mi = 0; mi < 4; ++mi)
                af[mi] = *(const short8*)&a_lds[(wr * 64 + mi * 16 + cl) * 64 + ks * 32 + g * 8];
#pragma unroll
            for (int ni = 0; ni < 2; ++ni)
                bfr[ni] = *(const short8*)&b_lds[(wc * 32 + ni * 16 + cl) * 64 + ks * 32 + g * 8];
#pragma unroll
            for (int mi = 0; mi < 4; ++mi)
#pragma unroll
                for (int ni = 0; ni < 2; ++ni)
                    acc[mi][ni] = __builtin_amdgcn_mfma_f32_16x16x32_bf16(
                        af[mi], bfr[ni], acc[mi][ni], 0, 0, 0);
        }
    }

    if (VSPLIT && colBase >= 1024) {
        // V range: write transposed, 4 consecutive rows -> one 8B store
#pragma unroll
        for (int mi = 0; mi < 4; ++mi) {
#pragma unroll
            for (int ni = 0; ni < 2; ++ni) {
                const int row0 = rowBase + wr * 64 + mi * 16 + g * 4;
                const int vcol = colBase + wc * 32 + ni * 16 + cl - 1024;
                const int bb = row0 >> 10, pos = row0 & 1023;
                const int h = vcol >> 6, d = vcol & 63;
                ushort4 o4 = { f2u(acc[mi][ni][0]), f2u(acc[mi][ni][1]),
                               f2u(acc[mi][ni][2]), f2u(acc[mi][ni][3]) };
                *(ushort4*)(vt + ((size_t)((bb * 8 + h) * 64 + d) << 10) + pos) = o4;
            }
        }
        return;
    }

#pragma unroll
    for (int mi = 0; mi < 4; ++mi) {
#pragma unroll
        for (int ni = 0; ni < 2; ++ni) {
            const int row0 = rowBase + wr * 64 + mi * 16 + g * 4;
            const int col = colBase + wc * 32 + ni * 16 + cl;
            const float bv = bias ? bias[col] : 0.0f;
#pragma unroll
            for (int j = 0; j < 4; ++j) {
                float vv = acc[mi][ni][j] + bv;
                if (ACT == 1) vv = gelu_f(vv);
                if (res) vv += res[(size_t)(row0 + j) * ldc + col];
                if constexpr (sizeof(TO) == 2)
                    ((unsigned short*)C)[(size_t)(row0 + j) * ldc + col] = f2u(vv);
                else
                    ((float*)C)[(size_t)(row0 + j) * ldc + col] = vv;
            }
        }
    }
}

// ---------------- BigBird attention (XCD swizzle + global-block key-split) --
// qk layout [B*L][1024]: q cols 0-511, k cols 512-1023. vt layout
// [(b*8+h)*64 + d][1024 pos]. O written in-place over q columns (middle
// blocks) or to o_part/lp_part scratch (m=0/15, split into two 8-tile
// halves along the key axis -- no-max softmax partials combine linearly;
// attn_combine merges them). 18 slots per (b,h): 0,1 = m=0 parts; 2,3 =
// m=15 parts; 4..17 = m=1..14. All slots of one (b,h) land on one XCD.
__global__ __launch_bounds__(256) void attn_kernel(
    bf16* qk, const bf16* __restrict__ vt, const int* __restrict__ rnd,
    bf16* __restrict__ o_part, float* __restrict__ lp_part)
{
    const int bid = blockIdx.x;
    const int xcd = bid & 7, kkk = bid >> 3;      // kkk in [0,144)
    const int bhg = kkk / 18, slot = kkk % 18;
    const int bh_idx = bhg * 8 + xcd;             // [0,64): b*8+h
    const int b = bh_idx >> 3, h = bh_idx & 7;
    const bool partial = slot < 4;
    const int m = partial ? ((slot < 2) ? 0 : 15) : (slot - 3);
    const int LD = 1024;

    __shared__ __attribute__((aligned(16))) unsigned short k_lds[64][72];  // [key][d]
    __shared__ __attribute__((aligned(16))) unsigned short vt_lds[64][72]; // [d][key]
    __shared__ __attribute__((aligned(16))) unsigned short p_lds[64][72];  // [q][key] (wave-private rows)
    __shared__ int sh_idx[16];
    __shared__ int sh_n;

    const int tid = threadIdx.x;
    if (tid == 0) {
        int tmp[16]; int cnt = 0;
        if (partial) {
            const int base = (slot & 1) * 8;
            for (int s = 0; s < 8; ++s) tmp[cnt++] = base + s;
        } else {
            const int cand[8] = { 0, 15, m - 1, m, m + 1,
                                  rnd[m * 3], rnd[m * 3 + 1], rnd[m * 3 + 2] };
            for (int s = 0; s < 8; ++s) {
                bool dup = false;
                for (int t2 = 0; t2 < cnt; ++t2) dup = dup || (tmp[t2] == cand[s]);
                if (!dup) tmp[cnt++] = cand[s];
            }
        }
        sh_n = cnt;
        for (int s = 0; s < cnt; ++s) sh_idx[s] = tmp[s];
    }

    const int w = tid >> 6, lane = tid & 63;
    const int cl = lane & 15;          // "column" lane index
    const int g  = lane >> 4;          // k-group / row-group index
    const size_t bh = (size_t)b * 1024;

    short8 qa0, qa1;
    {
        const bf16* qp = qk + (bh + m * 64 + w * 16 + cl) * LD + h * 64 + g * 8;
        qa0 = *(const short8*)(qp);
        qa1 = *(const short8*)(qp + 32);
    }

    f32x4 o_acc[4] = {};
    f32x4 lp = {};                      // per-lane partial denominator

    const int srow = tid >> 2, sseg = (tid & 3) << 4;   // staging map (K and V)
    const bf16* kbase = qk + 512 + h * 64;
    const bf16* vbase = vt + ((size_t)((b * 8 + h) * 64 + srow) << 10) + sseg;

    __syncthreads();                      // sh_idx ready; all Q reads done
    const int S = sh_n;

    // prefetch tile 0
    short8 kp0, kp1, vp0, vp1;
    {
        const int kb = sh_idx[0];
        const short8* ks8 = (const short8*)(kbase + (bh + kb * 64 + srow) * LD + sseg);
        kp0 = ks8[0]; kp1 = ks8[1];
        const short8* vs8 = (const short8*)(vbase + kb * 64);
        vp0 = vs8[0]; vp1 = vs8[1];
    }

    for (int s = 0; s < S; ++s) {
        // ---- write prefetched K/V regs to LDS (row-major, b128 each) ----
        *(short8*)&k_lds[srow][sseg] = kp0;
        *(short8*)&k_lds[srow][sseg + 8] = kp1;
        *(short8*)&vt_lds[srow][sseg] = vp0;
        *(short8*)&vt_lds[srow][sseg + 8] = vp1;
        __syncthreads();                  // barrier A: stage visible

        // ---- issue next tile's global loads (hidden under compute) ----
        if (s + 1 < S) {
            const int kb = sh_idx[s + 1];
            const short8* ks8 = (const short8*)(kbase + (bh + kb * 64 + srow) * LD + sseg);
            kp0 = ks8[0]; kp1 = ks8[1];
            const short8* vs8 = (const short8*)(vbase + kb * 64);
            vp0 = vs8[0]; vp1 = vs8[1];
        }

        // ---- QK^T: 4 key-tiles x 2 d-steps ----
        f32x4 sc[4];
        __builtin_amdgcn_s_setprio(1);
#pragma unroll
        for (int nt = 0; nt < 4; ++nt) {
            const short8 kb0 = *(const short8*)&k_lds[nt * 16 + cl][g * 8];
            const short8 kb1 = *(const short8*)&k_lds[nt * 16 + cl][32 + g * 8];
            f32x4 acc = {};
            acc = __builtin_amdgcn_mfma_f32_16x16x32_bf16(qa0, kb0, acc, 0, 0, 0);
            acc = __builtin_amdgcn_mfma_f32_16x16x32_bf16(qa1, kb1, acc, 0, 0, 0);
            sc[nt] = acc;
        }
        __builtin_amdgcn_s_setprio(0);

        // ---- p = exp(score), accumulate denominator partials ----
        f32x4 p[4];
#pragma unroll
        for (int nt = 0; nt < 4; ++nt) {
            p[nt].x = __expf(sc[nt].x);
            p[nt].y = __expf(sc[nt].y);
            p[nt].z = __expf(sc[nt].z);
            p[nt].w = __expf(sc[nt].w);
        }
        lp += p[0] + p[1] + p[2] + p[3];

        // ---- P -> bf16 -> LDS (wave-private rows; lgkm-ordered) ----
        {
            const int pr = w * 16 + g * 4;
#pragma unroll
            for (int nt = 0; nt < 4; ++nt) {
                p_lds[pr + 0][nt * 16 + cl] = f2u(p[nt].x);
                p_lds[pr + 1][nt * 16 + cl] = f2u(p[nt].y);
                p_lds[pr + 2][nt * 16 + cl] = f2u(p[nt].z);
                p_lds[pr + 3][nt * 16 + cl] = f2u(p[nt].w);
            }
        }

        // ---- PV: O += P @ V ----
        {
            const short8 pa0 = *(const short8*)&p_lds[w * 16 + cl][g * 8];
            const short8 pa1 = *(const short8*)&p_lds[w * 16 + cl][32 + g * 8];
            __builtin_amdgcn_s_setprio(1);
#pragma unroll
            for (int nt = 0; nt < 4; ++nt) {
                const short8 vb0 = *(const short8*)&vt_lds[nt * 16 + cl][g * 8];
                const short8 vb1 = *(const short8*)&vt_lds[nt * 16 + cl][32 + g * 8];
                o_acc[nt] = __builtin_amdgcn_mfma_f32_16x16x32_bf16(pa0, vb0, o_acc[nt], 0, 0, 0);
                o_acc[nt] = __builtin_amdgcn_mfma_f32_16x16x32_bf16(pa1, vb1, o_acc[nt], 0, 0, 0);
            }
            __builtin_amdgcn_s_setprio(0);
        }
        __syncthreads();       // barrier C: PV/QK reads done before next stage
    }

    // ---- reduce denominator over the 16 cl lanes ----
#pragma unroll
    for (int mask = 1; mask <= 8; mask <<= 1) {
        lp.x += __shfl_xor(lp.x, mask);
        lp.y += __shfl_xor(lp.y, mask);
        lp.z += __shfl_xor(lp.z, mask);
        lp.w += __shfl_xor(lp.w, mask);
    }

    if (partial) {
        // unnormalized partial -> scratch (bf16 o, f32 lp)
        const int ps = bh_idx * 4 + slot;
        unsigned short* op = (unsigned short*)o_part
            + ((size_t)ps * 64 + w * 16 + g * 4) * 64 + cl;
#pragma unroll
        for (int nt = 0; nt < 4; ++nt) {
            op[nt * 16 + 0 * 64] = f2u(o_acc[nt].x);
            op[nt * 16 + 1 * 64] = f2u(o_acc[nt].y);
            op[nt * 16 + 2 * 64] = f2u(o_acc[nt].z);
            op[nt * 16 + 3 * 64] = f2u(o_acc[nt].w);
        }
        if (cl == 0) {
            float* lpp = lp_part + ps * 64 + w * 16 + g * 4;
            lpp[0] = lp.x; lpp[1] = lp.y; lpp[2] = lp.z; lpp[3] = lp.w;
        }
        return;
    }

    f32x4 inv;
    inv.x = 1.0f / lp.x; inv.y = 1.0f / lp.y;
    inv.z = 1.0f / lp.z; inv.w = 1.0f / lp.w;
    const size_t orow = bh + m * 64 + w * 16 + g * 4;
    bf16* ob = qk + orow * LD + h * 64 + cl;
#pragma unroll
    for (int nt = 0; nt < 4; ++nt) {
        const f32x4 ov = o_acc[nt] * inv;
        ((unsigned short*)(ob))[nt * 16] = f2u(ov.x);
        ((unsigned short*)(ob + LD))[nt * 16] = f2u(ov.y);
        ((unsigned short*)(ob + 2 * LD))[nt * 16] = f2u(ov.z);
        ((unsigned short*)(ob + 3 * LD))[nt * 16] = f2u(ov.w);
    }
}

// ---------------- combine the split global-block partials --------------------
// grid (64, 2): (bh_idx, which m: 0->m=0, 1->m=15). 256 thr: q = t>>2,
// 16 d per thread. O = (o0 + o1) / (l0 + l1), write bf16 into qk q-cols.
__global__ __launch_bounds__(256) void attn_combine(
    const bf16* __restrict__ o_part, const float* __restrict__ lp_part,
    bf16* __restrict__ qk)
{
    const int bh_idx = blockIdx.x;
    const int which = blockIdx.y;
    const int b = bh_idx >> 3, h = bh_idx & 7;
    const int m = which ? 15 : 0;
    const int s0 = bh_idx * 4 + which * 2;
    const int t = threadIdx.x;
    const int q = t >> 2, d0 = (t & 3) << 4;

    const float l = lp_part[s0 * 64 + q] + lp_part[(s0 + 1) * 64 + q];
    const float inv = 1.0f / l;
    const bf16* p0 = o_part + ((size_t)s0 * 64 + q) * 64 + d0;
    const bf16* p1 = o_part + ((size_t)(s0 + 1) * 64 + q) * 64 + d0;
    bf16* dst = qk + ((size_t)(b * 1024 + m * 64 + q)) * 1024 + h * 64 + d0;

    const short8 a0 = *(const short8*)p0, a1 = *(const short8*)(p0 + 8);
    const short8 b0 = *(const short8*)p1, b1 = *(const short8*)(p1 + 8);
    short8 r0, r1;
#pragma unroll
    for (int i = 0; i < 8; ++i) {
        r0[i] = (short)f2u((u2f((unsigned short)a0[i]) + u2f((unsigned short)b0[i])) * inv);
        r1[i] = (short)f2u((u2f((unsigned short)a1[i]) + u2f((unsigned short)b1[i])) * inv);
    }
    *(short8*)dst = r0;
    *(short8*)(dst + 8) = r1;
}

// ---------------------------------------------------------------------------
extern "C" void kernel_launch(void* const* d_in, const int* in_sizes, int n_in,
                              void* d_out, int out_size, void* d_ws, size_t ws_size,
                              hipStream_t stream)
{
    (void)in_sizes; (void)n_in; (void)out_size; (void)ws_size;
    const float* inp  = (const float*)d_in[0];
    const float* ln1s = (const float*)d_in[2];
    const float* ln1b = (const float*)d_in[3];
    const float* Wq   = (const float*)d_in[4];
    const float* Wk   = (const float*)d_in[5];
    const float* Wv   = (const float*)d_in[6];
    const float* Wo   = (const float*)d_in[7];
    const float* ln2s = (const float*)d_in[8];
    const float* ln2b = (const float*)d_in[9];
    const float* W1   = (const float*)d_in[10];
    const float* b1   = (const float*)d_in[11];
    const float* W2   = (const float*)d_in[12];
    const float* b2   = (const float*)d_in[13];
    const int*  rnd   = (const int*)d_in[14];
    float* out = (float*)d_out;

    char* ws = (char*)d_ws;
    const size_t MB = 1024 * 1024;
    bf16* WqkvT  = (bf16*)(ws);            // 1.5 MB: [1536][512]
    bf16* WoT    = (bf16*)(ws + 2 * MB);   // 0.5 MB
    bf16* W1T    = (bf16*)(ws + 3 * MB);   // 1 MB: [1024][512]
    bf16* W2T    = (bf16*)(ws + 4 * MB);   // 1 MB: [512][1024]
    bf16* o_part = (bf16*)(ws + 5 * MB);   // 2 MB: [64*4][64][64]
    float* lp_part = (float*)(ws + 7 * MB);// 64 KB: [64*4][64]
    bf16* qk     = (bf16*)(ws + 8 * MB);   // 16 MB: [8192][1024] (q | k)
    bf16* vtb    = (bf16*)(ws + 24 * MB);  // 8 MB: [4096][1024] (V^T per b,h)
    bf16* y      = (bf16*)(ws + 8 * MB);   // alias qk (dead after Wo): LN2 out
    bf16* h1     = (bf16*)(ws + 16 * MB);  // 16 MB: MLP hidden
    bf16* xb     = (bf16*)d_out;           // LN1 out; d_out scratch until Wo GEMM

    wconv_all<<<dim3(32, 32, 6), 256, 0, stream>>>(Wq, Wk, Wv, Wo, W1, W2,
                                                   WqkvT, WoT, W1T, W2T);
    ln_kernel<<<8192, 128, 0, stream>>>(inp, ln1s, ln1b, xb);
    mfma_gemm<0, 1, bf16><<<1536, 256, 0, stream>>>(xb, 512, WqkvT, nullptr, nullptr, qk, 1024, 512, vtb, 24);
    attn_kernel<<<1152, 256, 0, stream>>>(qk, vtb, rnd, o_part, lp_part);
    attn_combine<<<dim3(64, 2), 256, 0, stream>>>(o_part, lp_part, qk);
    mfma_gemm<0, 0, float><<<512, 256, 0, stream>>>(qk, 1024, WoT, nullptr, inp, out, 512, 512, nullptr, 8);
    ln_kernel<<<8192, 128, 0, stream>>>(out, ln2s, ln2b, y);
    mfma_gemm<1, 0, bf16><<<1024, 256, 0, stream>>>(y, 512, W1T, b1, nullptr, h1, 1024, 512, nullptr, 16);
    mfma_gemm<0, 0, float><<<512, 256, 0, stream>>>(h1, 1024, W2T, b2, out, out, 512, 1024, nullptr, 8);
}

// Round 18
// 146.997 us; speedup vs baseline: 1.0700x; 1.0295x over previous
//
#include <hip/hip_runtime.h>
#include <hip/hip_bf16.h>

using bf16 = __hip_bfloat16;

typedef __attribute__((ext_vector_type(8))) short short8;   // 8 x bf16 (4 VGPR)
typedef __attribute__((ext_vector_type(4))) float f32x4;

#define DEVI __device__ __forceinline__

DEVI float u2f(unsigned short u) {
    union { unsigned int i; float f; } c;
    c.i = ((unsigned int)u) << 16;
    return c.f;
}

DEVI unsigned short f2u(float f) {
    union { float f; unsigned int i; } c;
    c.f = f;
    unsigned int x = c.i;
    unsigned int lsb = (x >> 16) & 1u;
    x += 0x7fffu + lsb;            // round-to-nearest-even
    return (unsigned short)(x >> 16);
}

DEVI float gelu_f(float x) {
    const float kA = 0.7978845608028654f;  // sqrt(2/pi)
    float inner = kA * (x + 0.044715f * x * x * x);
    return 0.5f * x * (1.0f + tanhf(inner));
}

DEVI void gload16(const void* g, void* l) {
    __builtin_amdgcn_global_load_lds(
        (const __attribute__((address_space(1))) void*)g,
        (__attribute__((address_space(3))) void*)l, 16, 0, 0);
}

// ---------------- fused prep: weight transpose-convert + LN1 ----------------
// 1D grid, 6144 blocks x 256 thr (BK=64 GEMMs unchanged -- this isolates the
// prep-fusion variable from round 16's bundled regression):
//   bid <  1024 : wconv z = bid>>8 (Wq x0.125, Wk, Wv, Wo), 16x16 tiles
//   bid <  1536 : wconv W1 (16 kt x 32 nt)
//   bid <  2048 : wconv W2 (32 kt x 16 nt)
//   bid >= 2048 : LN1, 2 rows per block (threads [0,128) and [128,256))
__global__ __launch_bounds__(256) void prep_kernel(
    const float* __restrict__ Wq, const float* __restrict__ Wk,
    const float* __restrict__ Wv, const float* __restrict__ Wo,
    const float* __restrict__ W1, const float* __restrict__ W2,
    bf16* __restrict__ WqkvT, bf16* __restrict__ WoT,
    bf16* __restrict__ W1T, bf16* __restrict__ W2T,
    const float* __restrict__ inp, const float* __restrict__ ln1s,
    const float* __restrict__ ln1b, bf16* __restrict__ xb)
{
    __shared__ float t[32][33];
    __shared__ float red[4];
    const int bid = blockIdx.x;

    if (bid < 2048) {
        int z, xt, yt;
        if (bid < 1024)      { z = bid >> 8; const int i = bid & 255;  xt = i >> 4; yt = i & 15; }
        else if (bid < 1536) { z = 4;        const int i = bid - 1024; xt = i >> 5; yt = i & 31; }
        else                 { z = 5;        const int i = bid - 1536; xt = i >> 4; yt = i & 15; }
        const float* W; bf16* WT; int K, N; float scale = 1.0f;
        switch (z) {
            case 0: W = Wq; WT = WqkvT;              K = 512;  N = 512;  scale = 0.125f; break;
            case 1: W = Wk; WT = WqkvT + 512 * 512;  K = 512;  N = 512;  break;
            case 2: W = Wv; WT = WqkvT + 1024 * 512; K = 512;  N = 512;  break;
            case 3: W = Wo; WT = WoT;                K = 512;  N = 512;  break;
            case 4: W = W1; WT = W1T;                K = 512;  N = 1024; break;
            default: W = W2; WT = W2T;               K = 1024; N = 512;  break;
        }
        const int kt = xt * 32, nt = yt * 32;
        const int tx = threadIdx.x & 31, ty = threadIdx.x >> 5;   // 32 x 8
#pragma unroll
        for (int p = 0; p < 4; ++p)
            t[ty + p * 8][tx] = W[(size_t)(kt + ty + p * 8) * N + nt + tx];
        __syncthreads();
#pragma unroll
        for (int p = 0; p < 4; ++p)
            ((unsigned short*)WT)[(size_t)(nt + ty + p * 8) * K + kt + tx] =
                f2u(t[tx][ty + p * 8] * scale);
        return;
    }

    // ---- LN1: 2 rows per block ----
    const int row = (bid - 2048) * 2 + (threadIdx.x >> 7);
    const int tl = threadIdx.x & 127;
    const int rb = (threadIdx.x >> 7) * 2;          // red base for this row
    const float4 r4 = ((const float4*)(inp + (size_t)row * 512))[tl];
    float v[4] = { r4.x, r4.y, r4.z, r4.w };

    float s = v[0] + v[1] + v[2] + v[3];
#pragma unroll
    for (int off = 32; off; off >>= 1) s += __shfl_xor(s, off);
    if ((threadIdx.x & 63) == 0) red[threadIdx.x >> 6] = s;
    __syncthreads();
    const float mean = (red[rb] + red[rb + 1]) * (1.0f / 512.0f);

    float c[4];
    float sq = 0.f;
#pragma unroll
    for (int i = 0; i < 4; ++i) { c[i] = v[i] - mean; sq += c[i] * c[i]; }
#pragma unroll
    for (int off = 32; off; off >>= 1) sq += __shfl_xor(sq, off);
    __syncthreads();
    if ((threadIdx.x & 63) == 0) red[threadIdx.x >> 6] = sq;
    __syncthreads();
    const float var = (red[rb] + red[rb + 1]) * (1.0f / 512.0f);
    const float rs = rsqrtf(var + 1e-6f);

    const float4 g4 = ((const float4*)ln1s)[tl];
    const float4 b4 = ((const float4*)ln1b)[tl];
    ushort4 o4;
    o4.x = f2u(c[0] * rs * g4.x + b4.x);
    o4.y = f2u(c[1] * rs * g4.y + b4.y);
    o4.z = f2u(c[2] * rs * g4.z + b4.z);
    o4.w = f2u(c[3] * rs * g4.w + b4.w);
    ((ushort4*)(xb + (size_t)row * 512))[tl] = o4;
}

// ---------------- LayerNorm: one row (D=512) per block, 128 thr x 4 elem ----
__global__ __launch_bounds__(128) void ln_kernel(
    const float* __restrict__ in, const float* __restrict__ gamma,
    const float* __restrict__ beta, bf16* __restrict__ out)
{
    const int row = blockIdx.x;
    const int t = threadIdx.x;
    const float4 r4 = ((const float4*)(in + (size_t)row * 512))[t];
    float v[4] = { r4.x, r4.y, r4.z, r4.w };

    __shared__ float red[2];
    float s = v[0] + v[1] + v[2] + v[3];
#pragma unroll
    for (int off = 32; off; off >>= 1) s += __shfl_xor(s, off);
    if ((t & 63) == 0) red[t >> 6] = s;
    __syncthreads();
    const float mean = (red[0] + red[1]) * (1.0f / 512.0f);

    float c[4];
    float sq = 0.f;
#pragma unroll
    for (int i = 0; i < 4; ++i) { c[i] = v[i] - mean; sq += c[i] * c[i]; }
#pragma unroll
    for (int off = 32; off; off >>= 1) sq += __shfl_xor(sq, off);
    __syncthreads();
    if ((t & 63) == 0) red[t >> 6] = sq;
    __syncthreads();
    const float var = (red[0] + red[1]) * (1.0f / 512.0f);
    const float rs = rsqrtf(var + 1e-6f);

    const float4 g4 = ((const float4*)gamma)[t];
    const float4 b4 = ((const float4*)beta)[t];
    ushort4 o4;
    o4.x = f2u(c[0] * rs * g4.x + b4.x);
    o4.y = f2u(c[1] * rs * g4.y + b4.y);
    o4.z = f2u(c[2] * rs * g4.z + b4.z);
    o4.w = f2u(c[3] * rs * g4.w + b4.w);
    ((ushort4*)(out + (size_t)row * 512))[t] = o4;
}

// ---------------- MFMA GEMM: C = act((A@BT^T) + bias) + res ----------------
// A [M][lda>=K] bf16, BT [N][K] bf16 (pre-transposed weights).
// Tile 128(M) x 64(N), BK=64, single-buffer (round-7 proven structure).
// 1D grid, XCD-swizzled (T1): each XCD owns NY/8 row-panels x ALL col-tiles,
// so a 128-row A-panel is fetched into exactly one XCD's L2 and reused by
// all NX col-blocks (instead of 8 XCDs each fetching a copy).
// VSPLIT: blocks with colBase >= 1024 write transposed V to vt.
template<int ACT, int VSPLIT, typename TO>  // ACT: 0 = none, 1 = gelu
__global__ __launch_bounds__(256) void mfma_gemm(
    const bf16* __restrict__ A, int lda, const bf16* __restrict__ BT,
    const float* __restrict__ bias, const float* __restrict__ res,
    TO* __restrict__ C, int ldc, int K, bf16* __restrict__ vt, int NX)
{
    __shared__ __attribute__((aligned(16))) bf16 a_lds[128 * 64];
    __shared__ __attribute__((aligned(16))) bf16 b_lds[64 * 64];

    const int bid = blockIdx.x;
    const int xcd = bid & 7;
    const int k = bid >> 3;
    const int ypg = (int)(gridDim.x >> 3) / NX;   // row-panels per XCD
    const int yb = xcd * ypg + k / NX;
    const int xb = k % NX;

    const int tid = threadIdx.x;
    const int w = tid >> 6, lane = tid & 63;
    const int cl = lane & 15, g = lane >> 4;
    const int wr = w >> 1, wc = w & 1;
    const int rowBase = yb * 128;
    const int colBase = xb * 64;
    const int lr = tid >> 3;            // 0..31: staging row within issue
    const int lc = (tid & 7) << 3;      // staging col (elems): 0,8,...,56

    f32x4 acc[4][2] = {};

    for (int k0 = 0; k0 < K; k0 += 64) {
        __syncthreads();
#pragma unroll
        for (int i = 0; i < 4; ++i)
            gload16(A + (size_t)(rowBase + i * 32 + lr) * lda + k0 + lc,
                    &a_lds[(i * 32 + lr) * 64 + lc]);
#pragma unroll
        for (int i = 0; i < 2; ++i)
            gload16(BT + (size_t)(colBase + i * 32 + lr) * K + k0 + lc,
                    &b_lds[(i * 32 + lr) * 64 + lc]);
        __syncthreads();

#pragma unroll
        for (int ks = 0; ks < 2; ++ks) {
            short8 af[4], bfr[2];
#pragma unroll
            for (int mi = 0; mi < 4; ++mi)
                af[mi] = *(const short8*)&a_lds[(wr * 64 + mi * 16 + cl) * 64 + ks * 32 + g * 8];
#pragma unroll
            for (int ni = 0; ni < 2; ++ni)
                bfr[ni] = *(const short8*)&b_lds[(wc * 32 + ni * 16 + cl) * 64 + ks * 32 + g * 8];
#pragma unroll
            for (int mi = 0; mi < 4; ++mi)
#pragma unroll
                for (int ni = 0; ni < 2; ++ni)
                    acc[mi][ni] = __builtin_amdgcn_mfma_f32_16x16x32_bf16(
                        af[mi], bfr[ni], acc[mi][ni], 0, 0, 0);
        }
    }

    if (VSPLIT && colBase >= 1024) {
        // V range: write transposed, 4 consecutive rows -> one 8B store
#pragma unroll
        for (int mi = 0; mi < 4; ++mi) {
#pragma unroll
            for (int ni = 0; ni < 2; ++ni) {
                const int row0 = rowBase + wr * 64 + mi * 16 + g * 4;
                const int vcol = colBase + wc * 32 + ni * 16 + cl - 1024;
                const int bb = row0 >> 10, pos = row0 & 1023;
                const int h = vcol >> 6, d = vcol & 63;
                ushort4 o4 = { f2u(acc[mi][ni][0]), f2u(acc[mi][ni][1]),
                               f2u(acc[mi][ni][2]), f2u(acc[mi][ni][3]) };
                *(ushort4*)(vt + ((size_t)((bb * 8 + h) * 64 + d) << 10) + pos) = o4;
            }
        }
        return;
    }

#pragma unroll
    for (int mi = 0; mi < 4; ++mi) {
#pragma unroll
        for (int ni = 0; ni < 2; ++ni) {
            const int row0 = rowBase + wr * 64 + mi * 16 + g * 4;
            const int col = colBase + wc * 32 + ni * 16 + cl;
            const float bv = bias ? bias[col] : 0.0f;
#pragma unroll
            for (int j = 0; j < 4; ++j) {
                float vv = acc[mi][ni][j] + bv;
                if (ACT == 1) vv = gelu_f(vv);
                if (res) vv += res[(size_t)(row0 + j) * ldc + col];
                if constexpr (sizeof(TO) == 2)
                    ((unsigned short*)C)[(size_t)(row0 + j) * ldc + col] = f2u(vv);
                else
                    ((float*)C)[(size_t)(row0 + j) * ldc + col] = vv;
            }
        }
    }
}

// ---------------- BigBird attention (XCD swizzle + global-block key-split) --
// qk layout [B*L][1024]: q cols 0-511, k cols 512-1023. vt layout
// [(b*8+h)*64 + d][1024 pos]. O written in-place over q columns (middle
// blocks) or to o_part/lp_part scratch (m=0/15, split into two 8-tile
// halves along the key axis -- no-max softmax partials combine linearly;
// attn_combine merges them). 18 slots per (b,h): 0,1 = m=0 parts; 2,3 =
// m=15 parts; 4..17 = m=1..14. All slots of one (b,h) land on one XCD.
__global__ __launch_bounds__(256) void attn_kernel(
    bf16* qk, const bf16* __restrict__ vt, const int* __restrict__ rnd,
    bf16* __restrict__ o_part, float* __restrict__ lp_part)
{
    const int bid = blockIdx.x;
    const int xcd = bid & 7, kkk = bid >> 3;      // kkk in [0,144)
    const int bhg = kkk / 18, slot = kkk % 18;
    const int bh_idx = bhg * 8 + xcd;             // [0,64): b*8+h
    const int b = bh_idx >> 3, h = bh_idx & 7;
    const bool partial = slot < 4;
    const int m = partial ? ((slot < 2) ? 0 : 15) : (slot - 3);
    const int LD = 1024;

    __shared__ __attribute__((aligned(16))) unsigned short k_lds[64][72];  // [key][d]
    __shared__ __attribute__((aligned(16))) unsigned short vt_lds[64][72]; // [d][key]
    __shared__ __attribute__((aligned(16))) unsigned short p_lds[64][72];  // [q][key] (wave-private rows)
    __shared__ int sh_idx[16];
    __shared__ int sh_n;

    const int tid = threadIdx.x;
    if (tid == 0) {
        int tmp[16]; int cnt = 0;
        if (partial) {
            const int base = (slot & 1) * 8;
            for (int s = 0; s < 8; ++s) tmp[cnt++] = base + s;
        } else {
            const int cand[8] = { 0, 15, m - 1, m, m + 1,
                                  rnd[m * 3], rnd[m * 3 + 1], rnd[m * 3 + 2] };
            for (int s = 0; s < 8; ++s) {
                bool dup = false;
                for (int t2 = 0; t2 < cnt; ++t2) dup = dup || (tmp[t2] == cand[s]);
                if (!dup) tmp[cnt++] = cand[s];
            }
        }
        sh_n = cnt;
        for (int s = 0; s < cnt; ++s) sh_idx[s] = tmp[s];
    }

    const int w = tid >> 6, lane = tid & 63;
    const int cl = lane & 15;          // "column" lane index
    const int g  = lane >> 4;          // k-group / row-group index
    const size_t bh = (size_t)b * 1024;

    short8 qa0, qa1;
    {
        const bf16* qp = qk + (bh + m * 64 + w * 16 + cl) * LD + h * 64 + g * 8;
        qa0 = *(const short8*)(qp);
        qa1 = *(const short8*)(qp + 32);
    }

    f32x4 o_acc[4] = {};
    f32x4 lp = {};                      // per-lane partial denominator

    const int srow = tid >> 2, sseg = (tid & 3) << 4;   // staging map (K and V)
    const bf16* kbase = qk + 512 + h * 64;
    const bf16* vbase = vt + ((size_t)((b * 8 + h) * 64 + srow) << 10) + sseg;

    __syncthreads();                      // sh_idx ready; all Q reads done
    const int S = sh_n;

    // prefetch tile 0
    short8 kp0, kp1, vp0, vp1;
    {
        const int kb = sh_idx[0];
        const short8* ks8 = (const short8*)(kbase + (bh + kb * 64 + srow) * LD + sseg);
        kp0 = ks8[0]; kp1 = ks8[1];
        const short8* vs8 = (const short8*)(vbase + kb * 64);
        vp0 = vs8[0]; vp1 = vs8[1];
    }

    for (int s = 0; s < S; ++s) {
        // ---- write prefetched K/V regs to LDS (row-major, b128 each) ----
        *(short8*)&k_lds[srow][sseg] = kp0;
        *(short8*)&k_lds[srow][sseg + 8] = kp1;
        *(short8*)&vt_lds[srow][sseg] = vp0;
        *(short8*)&vt_lds[srow][sseg + 8] = vp1;
        __syncthreads();                  // barrier A: stage visible

        // ---- issue next tile's global loads (hidden under compute) ----
        if (s + 1 < S) {
            const int kb = sh_idx[s + 1];
            const short8* ks8 = (const short8*)(kbase + (bh + kb * 64 + srow) * LD + sseg);
            kp0 = ks8[0]; kp1 = ks8[1];
            const short8* vs8 = (const short8*)(vbase + kb * 64);
            vp0 = vs8[0]; vp1 = vs8[1];
        }

        // ---- QK^T: 4 key-tiles x 2 d-steps ----
        f32x4 sc[4];
        __builtin_amdgcn_s_setprio(1);
#pragma unroll
        for (int nt = 0; nt < 4; ++nt) {
            const short8 kb0 = *(const short8*)&k_lds[nt * 16 + cl][g * 8];
            const short8 kb1 = *(const short8*)&k_lds[nt * 16 + cl][32 + g * 8];
            f32x4 acc = {};
            acc = __builtin_amdgcn_mfma_f32_16x16x32_bf16(qa0, kb0, acc, 0, 0, 0);
            acc = __builtin_amdgcn_mfma_f32_16x16x32_bf16(qa1, kb1, acc, 0, 0, 0);
            sc[nt] = acc;
        }
        __builtin_amdgcn_s_setprio(0);

        // ---- p = exp(score), accumulate denominator partials ----
        f32x4 p[4];
#pragma unroll
        for (int nt = 0; nt < 4; ++nt) {
            p[nt].x = __expf(sc[nt].x);
            p[nt].y = __expf(sc[nt].y);
            p[nt].z = __expf(sc[nt].z);
            p[nt].w = __expf(sc[nt].w);
        }
        lp += p[0] + p[1] + p[2] + p[3];

        // ---- P -> bf16 -> LDS (wave-private rows; lgkm-ordered) ----
        {
            const int pr = w * 16 + g * 4;
#pragma unroll
            for (int nt = 0; nt < 4; ++nt) {
                p_lds[pr + 0][nt * 16 + cl] = f2u(p[nt].x);
                p_lds[pr + 1][nt * 16 + cl] = f2u(p[nt].y);
                p_lds[pr + 2][nt * 16 + cl] = f2u(p[nt].z);
                p_lds[pr + 3][nt * 16 + cl] = f2u(p[nt].w);
            }
        }

        // ---- PV: O += P @ V ----
        {
            const short8 pa0 = *(const short8*)&p_lds[w * 16 + cl][g * 8];
            const short8 pa1 = *(const short8*)&p_lds[w * 16 + cl][32 + g * 8];
            __builtin_amdgcn_s_setprio(1);
#pragma unroll
            for (int nt = 0; nt < 4; ++nt) {
                const short8 vb0 = *(const short8*)&vt_lds[nt * 16 + cl][g * 8];
                const short8 vb1 = *(const short8*)&vt_lds[nt * 16 + cl][32 + g * 8];
                o_acc[nt] = __builtin_amdgcn_mfma_f32_16x16x32_bf16(pa0, vb0, o_acc[nt], 0, 0, 0);
                o_acc[nt] = __builtin_amdgcn_mfma_f32_16x16x32_bf16(pa1, vb1, o_acc[nt], 0, 0, 0);
            }
            __builtin_amdgcn_s_setprio(0);
        }
        __syncthreads();       // barrier C: PV/QK reads done before next stage
    }

    // ---- reduce denominator over the 16 cl lanes ----
#pragma unroll
    for (int mask = 1; mask <= 8; mask <<= 1) {
        lp.x += __shfl_xor(lp.x, mask);
        lp.y += __shfl_xor(lp.y, mask);
        lp.z += __shfl_xor(lp.z, mask);
        lp.w += __shfl_xor(lp.w, mask);
    }

    if (partial) {
        // unnormalized partial -> scratch (bf16 o, f32 lp)
        const int ps = bh_idx * 4 + slot;
        unsigned short* op = (unsigned short*)o_part
            + ((size_t)ps * 64 + w * 16 + g * 4) * 64 + cl;
#pragma unroll
        for (int nt = 0; nt < 4; ++nt) {
            op[nt * 16 + 0 * 64] = f2u(o_acc[nt].x);
            op[nt * 16 + 1 * 64] = f2u(o_acc[nt].y);
            op[nt * 16 + 2 * 64] = f2u(o_acc[nt].z);
            op[nt * 16 + 3 * 64] = f2u(o_acc[nt].w);
        }
        if (cl == 0) {
            float* lpp = lp_part + ps * 64 + w * 16 + g * 4;
            lpp[0] = lp.x; lpp[1] = lp.y; lpp[2] = lp.z; lpp[3] = lp.w;
        }
        return;
    }

    f32x4 inv;
    inv.x = 1.0f / lp.x; inv.y = 1.0f / lp.y;
    inv.z = 1.0f / lp.z; inv.w = 1.0f / lp.w;
    const size_t orow = bh + m * 64 + w * 16 + g * 4;
    bf16* ob = qk + orow * LD + h * 64 + cl;
#pragma unroll
    for (int nt = 0; nt < 4; ++nt) {
        const f32x4 ov = o_acc[nt] * inv;
        ((unsigned short*)(ob))[nt * 16] = f2u(ov.x);
        ((unsigned short*)(ob + LD))[nt * 16] = f2u(ov.y);
        ((unsigned short*)(ob + 2 * LD))[nt * 16] = f2u(ov.z);
        ((unsigned short*)(ob + 3 * LD))[nt * 16] = f2u(ov.w);
    }
}

// ---------------- combine the split global-block partials --------------------
// grid (64, 2): (bh_idx, which m: 0->m=0, 1->m=15). 256 thr: q = t>>2,
// 16 d per thread. O = (o0 + o1) / (l0 + l1), write bf16 into qk q-cols.
__global__ __launch_bounds__(256) void attn_combine(
    const bf16* __restrict__ o_part, const float* __restrict__ lp_part,
    bf16* __restrict__ qk)
{
    const int bh_idx = blockIdx.x;
    const int which = blockIdx.y;
    const int b = bh_idx >> 3, h = bh_idx & 7;
    const int m = which ? 15 : 0;
    const int s0 = bh_idx * 4 + which * 2;
    const int t = threadIdx.x;
    const int q = t >> 2, d0 = (t & 3) << 4;

    const float l = lp_part[s0 * 64 + q] + lp_part[(s0 + 1) * 64 + q];
    const float inv = 1.0f / l;
    const bf16* p0 = o_part + ((size_t)s0 * 64 + q) * 64 + d0;
    const bf16* p1 = o_part + ((size_t)(s0 + 1) * 64 + q) * 64 + d0;
    bf16* dst = qk + ((size_t)(b * 1024 + m * 64 + q)) * 1024 + h * 64 + d0;

    const short8 a0 = *(const short8*)p0, a1 = *(const short8*)(p0 + 8);
    const short8 b0 = *(const short8*)p1, b1 = *(const short8*)(p1 + 8);
    short8 r0, r1;
#pragma unroll
    for (int i = 0; i < 8; ++i) {
        r0[i] = (short)f2u((u2f((unsigned short)a0[i]) + u2f((unsigned short)b0[i])) * inv);
        r1[i] = (short)f2u((u2f((unsigned short)a1[i]) + u2f((unsigned short)b1[i])) * inv);
    }
    *(short8*)dst = r0;
    *(short8*)(dst + 8) = r1;
}

// ---------------------------------------------------------------------------
extern "C" void kernel_launch(void* const* d_in, const int* in_sizes, int n_in,
                              void* d_out, int out_size, void* d_ws, size_t ws_size,
                              hipStream_t stream)
{
    (void)in_sizes; (void)n_in; (void)out_size; (void)ws_size;
    const float* inp  = (const float*)d_in[0];
    const float* ln1s = (const float*)d_in[2];
    const float* ln1b = (const float*)d_in[3];
    const float* Wq   = (const float*)d_in[4];
    const float* Wk   = (const float*)d_in[5];
    const float* Wv   = (const float*)d_in[6];
    const float* Wo   = (const float*)d_in[7];
    const float* ln2s = (const float*)d_in[8];
    const float* ln2b = (const float*)d_in[9];
    const float* W1   = (const float*)d_in[10];
    const float* b1   = (const float*)d_in[11];
    const float* W2   = (const float*)d_in[12];
    const float* b2   = (const float*)d_in[13];
    const int*  rnd   = (const int*)d_in[14];
    float* out = (float*)d_out;

    char* ws = (char*)d_ws;
    const size_t MB = 1024 * 1024;
    bf16* WqkvT  = (bf16*)(ws);            // 1.5 MB: [1536][512]
    bf16* WoT    = (bf16*)(ws + 2 * MB);   // 0.5 MB
    bf16* W1T    = (bf16*)(ws + 3 * MB);   // 1 MB: [1024][512]
    bf16* W2T    = (bf16*)(ws + 4 * MB);   // 1 MB: [512][1024]
    bf16* o_part = (bf16*)(ws + 5 * MB);   // 2 MB: [64*4][64][64]
    float* lp_part = (float*)(ws + 7 * MB);// 64 KB: [64*4][64]
    bf16* qk     = (bf16*)(ws + 8 * MB);   // 16 MB: [8192][1024] (q | k)
    bf16* vtb    = (bf16*)(ws + 24 * MB);  // 8 MB: [4096][1024] (V^T per b,h)
    bf16* y      = (bf16*)(ws + 8 * MB);   // alias qk (dead after Wo): LN2 out
    bf16* h1     = (bf16*)(ws + 16 * MB);  // 16 MB: MLP hidden
    bf16* xb     = (bf16*)d_out;           // LN1 out; d_out scratch until Wo GEMM

    prep_kernel<<<6144, 256, 0, stream>>>(Wq, Wk, Wv, Wo, W1, W2,
                                          WqkvT, WoT, W1T, W2T,
                                          inp, ln1s, ln1b, xb);
    mfma_gemm<0, 1, bf16><<<1536, 256, 0, stream>>>(xb, 512, WqkvT, nullptr, nullptr, qk, 1024, 512, vtb, 24);
    attn_kernel<<<1152, 256, 0, stream>>>(qk, vtb, rnd, o_part, lp_part);
    attn_combine<<<dim3(64, 2), 256, 0, stream>>>(o_part, lp_part, qk);
    mfma_gemm<0, 0, float><<<512, 256, 0, stream>>>(qk, 1024, WoT, nullptr, inp, out, 512, 512, nullptr, 8);
    ln_kernel<<<8192, 128, 0, stream>>>(out, ln2s, ln2b, y);
    mfma_gemm<1, 0, bf16><<<1024, 256, 0, stream>>>(y, 512, W1T, b1, nullptr, h1, 1024, 512, nullptr, 16);
    mfma_gemm<0, 0, float><<<512, 256, 0, stream>>>(h1, 1024, W2T, b2, out, out, 512, 1024, nullptr, 8);
}

// Round 19
// 146.921 us; speedup vs baseline: 1.0706x; 1.0005x over previous
//
#include <hip/hip_runtime.h>
#include <hip/hip_bf16.h>

using bf16 = __hip_bfloat16;

typedef __attribute__((ext_vector_type(8))) short short8;   // 8 x bf16 (4 VGPR)
typedef __attribute__((ext_vector_type(4))) float f32x4;

#define DEVI __device__ __forceinline__

DEVI float u2f(unsigned short u) {
    union { unsigned int i; float f; } c;
    c.i = ((unsigned int)u) << 16;
    return c.f;
}

DEVI unsigned short f2u(float f) {
    union { float f; unsigned int i; } c;
    c.f = f;
    unsigned int x = c.i;
    unsigned int lsb = (x >> 16) & 1u;
    x += 0x7fffu + lsb;            // round-to-nearest-even
    return (unsigned short)(x >> 16);
}

DEVI float gelu_f(float x) {
    const float kA = 0.7978845608028654f;  // sqrt(2/pi)
    float inner = kA * (x + 0.044715f * x * x * x);
    return 0.5f * x * (1.0f + tanhf(inner));
}

DEVI void gload16(const void* g, void* l) {
    __builtin_amdgcn_global_load_lds(
        (const __attribute__((address_space(1))) void*)g,
        (__attribute__((address_space(3))) void*)l, 16, 0, 0);
}

// ---------------- fused prep: weight transpose-convert + LN1 ----------------
// 1D grid, 6144 blocks x 256 thr:
//   bid <  1024 : wconv z = bid>>8 (Wq x0.125, Wk, Wv, Wo), 16x16 tiles
//   bid <  1536 : wconv W1 (16 kt x 32 nt)
//   bid <  2048 : wconv W2 (32 kt x 16 nt)
//   bid >= 2048 : LN1, 2 rows per block (threads [0,128) and [128,256))
__global__ __launch_bounds__(256) void prep_kernel(
    const float* __restrict__ Wq, const float* __restrict__ Wk,
    const float* __restrict__ Wv, const float* __restrict__ Wo,
    const float* __restrict__ W1, const float* __restrict__ W2,
    bf16* __restrict__ WqkvT, bf16* __restrict__ WoT,
    bf16* __restrict__ W1T, bf16* __restrict__ W2T,
    const float* __restrict__ inp, const float* __restrict__ ln1s,
    const float* __restrict__ ln1b, bf16* __restrict__ xb)
{
    __shared__ float t[32][33];
    __shared__ float red[4];
    const int bid = blockIdx.x;

    if (bid < 2048) {
        int z, xt, yt;
        if (bid < 1024)      { z = bid >> 8; const int i = bid & 255;  xt = i >> 4; yt = i & 15; }
        else if (bid < 1536) { z = 4;        const int i = bid - 1024; xt = i >> 5; yt = i & 31; }
        else                 { z = 5;        const int i = bid - 1536; xt = i >> 4; yt = i & 15; }
        const float* W; bf16* WT; int K, N; float scale = 1.0f;
        switch (z) {
            case 0: W = Wq; WT = WqkvT;              K = 512;  N = 512;  scale = 0.125f; break;
            case 1: W = Wk; WT = WqkvT + 512 * 512;  K = 512;  N = 512;  break;
            case 2: W = Wv; WT = WqkvT + 1024 * 512; K = 512;  N = 512;  break;
            case 3: W = Wo; WT = WoT;                K = 512;  N = 512;  break;
            case 4: W = W1; WT = W1T;                K = 512;  N = 1024; break;
            default: W = W2; WT = W2T;               K = 1024; N = 512;  break;
        }
        const int kt = xt * 32, nt = yt * 32;
        const int tx = threadIdx.x & 31, ty = threadIdx.x >> 5;   // 32 x 8
#pragma unroll
        for (int p = 0; p < 4; ++p)
            t[ty + p * 8][tx] = W[(size_t)(kt + ty + p * 8) * N + nt + tx];
        __syncthreads();
#pragma unroll
        for (int p = 0; p < 4; ++p)
            ((unsigned short*)WT)[(size_t)(nt + ty + p * 8) * K + kt + tx] =
                f2u(t[tx][ty + p * 8] * scale);
        return;
    }

    // ---- LN1: 2 rows per block ----
    const int row = (bid - 2048) * 2 + (threadIdx.x >> 7);
    const int tl = threadIdx.x & 127;
    const int rb = (threadIdx.x >> 7) * 2;          // red base for this row
    const float4 r4 = ((const float4*)(inp + (size_t)row * 512))[tl];
    float v[4] = { r4.x, r4.y, r4.z, r4.w };

    float s = v[0] + v[1] + v[2] + v[3];
#pragma unroll
    for (int off = 32; off; off >>= 1) s += __shfl_xor(s, off);
    if ((threadIdx.x & 63) == 0) red[threadIdx.x >> 6] = s;
    __syncthreads();
    const float mean = (red[rb] + red[rb + 1]) * (1.0f / 512.0f);

    float c[4];
    float sq = 0.f;
#pragma unroll
    for (int i = 0; i < 4; ++i) { c[i] = v[i] - mean; sq += c[i] * c[i]; }
#pragma unroll
    for (int off = 32; off; off >>= 1) sq += __shfl_xor(sq, off);
    __syncthreads();
    if ((threadIdx.x & 63) == 0) red[threadIdx.x >> 6] = sq;
    __syncthreads();
    const float var = (red[rb] + red[rb + 1]) * (1.0f / 512.0f);
    const float rs = rsqrtf(var + 1e-6f);

    const float4 g4 = ((const float4*)ln1s)[tl];
    const float4 b4 = ((const float4*)ln1b)[tl];
    ushort4 o4;
    o4.x = f2u(c[0] * rs * g4.x + b4.x);
    o4.y = f2u(c[1] * rs * g4.y + b4.y);
    o4.z = f2u(c[2] * rs * g4.z + b4.z);
    o4.w = f2u(c[3] * rs * g4.w + b4.w);
    ((ushort4*)(xb + (size_t)row * 512))[tl] = o4;
}

// ---------------- LayerNorm: 2 rows per block, 256 thr (prep-LN shape) ------
__global__ __launch_bounds__(256) void ln_kernel(
    const float* __restrict__ in, const float* __restrict__ gamma,
    const float* __restrict__ beta, bf16* __restrict__ out)
{
    __shared__ float red[4];
    const int row = blockIdx.x * 2 + (threadIdx.x >> 7);
    const int tl = threadIdx.x & 127;
    const int rb = (threadIdx.x >> 7) * 2;
    const float4 r4 = ((const float4*)(in + (size_t)row * 512))[tl];
    float v[4] = { r4.x, r4.y, r4.z, r4.w };

    float s = v[0] + v[1] + v[2] + v[3];
#pragma unroll
    for (int off = 32; off; off >>= 1) s += __shfl_xor(s, off);
    if ((threadIdx.x & 63) == 0) red[threadIdx.x >> 6] = s;
    __syncthreads();
    const float mean = (red[rb] + red[rb + 1]) * (1.0f / 512.0f);

    float c[4];
    float sq = 0.f;
#pragma unroll
    for (int i = 0; i < 4; ++i) { c[i] = v[i] - mean; sq += c[i] * c[i]; }
#pragma unroll
    for (int off = 32; off; off >>= 1) sq += __shfl_xor(sq, off);
    __syncthreads();
    if ((threadIdx.x & 63) == 0) red[threadIdx.x >> 6] = sq;
    __syncthreads();
    const float var = (red[rb] + red[rb + 1]) * (1.0f / 512.0f);
    const float rs = rsqrtf(var + 1e-6f);

    const float4 g4 = ((const float4*)gamma)[tl];
    const float4 b4 = ((const float4*)beta)[tl];
    ushort4 o4;
    o4.x = f2u(c[0] * rs * g4.x + b4.x);
    o4.y = f2u(c[1] * rs * g4.y + b4.y);
    o4.z = f2u(c[2] * rs * g4.z + b4.z);
    o4.w = f2u(c[3] * rs * g4.w + b4.w);
    ((ushort4*)(out + (size_t)row * 512))[tl] = o4;
}

// ---------------- MFMA GEMM: C = act((A@BT^T) + bias) + res ----------------
// A [M][lda>=K] bf16, BT [N][K] bf16 (pre-transposed weights).
// Tile 128(M) x 64(N), BK=64, single-buffer (round-7 proven structure).
// 1D grid, XCD-swizzled (T1): each XCD owns NY/8 row-panels x ALL col-tiles,
// so a 128-row A-panel is fetched into exactly one XCD's L2 and reused by
// all NX col-blocks (instead of 8 XCDs each fetching a copy).
// VSPLIT: blocks with colBase >= 1024 write transposed V to vt.
template<int ACT, int VSPLIT, typename TO>  // ACT: 0 = none, 1 = gelu
__global__ __launch_bounds__(256) void mfma_gemm(
    const bf16* __restrict__ A, int lda, const bf16* __restrict__ BT,
    const float* __restrict__ bias, const float* __restrict__ res,
    TO* __restrict__ C, int ldc, int K, bf16* __restrict__ vt, int NX)
{
    __shared__ __attribute__((aligned(16))) bf16 a_lds[128 * 64];
    __shared__ __attribute__((aligned(16))) bf16 b_lds[64 * 64];

    const int bid = blockIdx.x;
    const int xcd = bid & 7;
    const int k = bid >> 3;
    const int ypg = (int)(gridDim.x >> 3) / NX;   // row-panels per XCD
    const int yb = xcd * ypg + k / NX;
    const int xb = k % NX;

    const int tid = threadIdx.x;
    const int w = tid >> 6, lane = tid & 63;
    const int cl = lane & 15, g = lane >> 4;
    const int wr = w >> 1, wc = w & 1;
    const int rowBase = yb * 128;
    const int colBase = xb * 64;
    const int lr = tid >> 3;            // 0..31: staging row within issue
    const int lc = (tid & 7) << 3;      // staging col (elems): 0,8,...,56

    f32x4 acc[4][2] = {};

    for (int k0 = 0; k0 < K; k0 += 64) {
        __syncthreads();
#pragma unroll
        for (int i = 0; i < 4; ++i)
            gload16(A + (size_t)(rowBase + i * 32 + lr) * lda + k0 + lc,
                    &a_lds[(i * 32 + lr) * 64 + lc]);
#pragma unroll
        for (int i = 0; i < 2; ++i)
            gload16(BT + (size_t)(colBase + i * 32 + lr) * K + k0 + lc,
                    &b_lds[(i * 32 + lr) * 64 + lc]);
        __syncthreads();

#pragma unroll
        for (int ks = 0; ks < 2; ++ks) {
            short8 af[4], bfr[2];
#pragma unroll
            for (int mi = 0; mi < 4; ++mi)
                af[mi] = *(const short8*)&a_lds[(wr * 64 + mi * 16 + cl) * 64 + ks * 32 + g * 8];
#pragma unroll
            for (int ni = 0; ni < 2; ++ni)
                bfr[ni] = *(const short8*)&b_lds[(wc * 32 + ni * 16 + cl) * 64 + ks * 32 + g * 8];
#pragma unroll
            for (int mi = 0; mi < 4; ++mi)
#pragma unroll
                for (int ni = 0; ni < 2; ++ni)
                    acc[mi][ni] = __builtin_amdgcn_mfma_f32_16x16x32_bf16(
                        af[mi], bfr[ni], acc[mi][ni], 0, 0, 0);
        }
    }

    if (VSPLIT && colBase >= 1024) {
        // V range: write transposed, 4 consecutive rows -> one 8B store
#pragma unroll
        for (int mi = 0; mi < 4; ++mi) {
#pragma unroll
            for (int ni = 0; ni < 2; ++ni) {
                const int row0 = rowBase + wr * 64 + mi * 16 + g * 4;
                const int vcol = colBase + wc * 32 + ni * 16 + cl - 1024;
                const int bb = row0 >> 10, pos = row0 & 1023;
                const int h = vcol >> 6, d = vcol & 63;
                ushort4 o4 = { f2u(acc[mi][ni][0]), f2u(acc[mi][ni][1]),
                               f2u(acc[mi][ni][2]), f2u(acc[mi][ni][3]) };
                *(ushort4*)(vt + ((size_t)((bb * 8 + h) * 64 + d) << 10) + pos) = o4;
            }
        }
        return;
    }

#pragma unroll
    for (int mi = 0; mi < 4; ++mi) {
#pragma unroll
        for (int ni = 0; ni < 2; ++ni) {
            const int row0 = rowBase + wr * 64 + mi * 16 + g * 4;
            const int col = colBase + wc * 32 + ni * 16 + cl;
            const float bv = bias ? bias[col] : 0.0f;
#pragma unroll
            for (int j = 0; j < 4; ++j) {
                float vv = acc[mi][ni][j] + bv;
                if (ACT == 1) vv = gelu_f(vv);
                if (res) vv += res[(size_t)(row0 + j) * ldc + col];
                if constexpr (sizeof(TO) == 2)
                    ((unsigned short*)C)[(size_t)(row0 + j) * ldc + col] = f2u(vv);
                else
                    ((float*)C)[(size_t)(row0 + j) * ldc + col] = vv;
            }
        }
    }
}

// ---------------- BigBird attention (XCD swizzle + global-block key-split) --
// qk layout [B*L][1024]: q cols 0-511, k cols 512-1023. vt layout
// [(b*8+h)*64 + d][1024 pos]. O written in-place over q columns (middle
// blocks) or to o_part/lp_part scratch (m=0/15, split into two 8-tile
// halves along the key axis -- no-max softmax partials combine linearly;
// attn_combine merges them). 18 slots per (b,h): 0,1 = m=0 parts; 2,3 =
// m=15 parts; 4..17 = m=1..14. All slots of one (b,h) land on one XCD.
__global__ __launch_bounds__(256) void attn_kernel(
    bf16* qk, const bf16* __restrict__ vt, const int* __restrict__ rnd,
    bf16* __restrict__ o_part, float* __restrict__ lp_part)
{
    const int bid = blockIdx.x;
    const int xcd = bid & 7, kkk = bid >> 3;      // kkk in [0,144)
    const int bhg = kkk / 18, slot = kkk % 18;
    const int bh_idx = bhg * 8 + xcd;             // [0,64): b*8+h
    const int b = bh_idx >> 3, h = bh_idx & 7;
    const bool partial = slot < 4;
    const int m = partial ? ((slot < 2) ? 0 : 15) : (slot - 3);
    const int LD = 1024;

    __shared__ __attribute__((aligned(16))) unsigned short k_lds[64][72];  // [key][d]
    __shared__ __attribute__((aligned(16))) unsigned short vt_lds[64][72]; // [d][key]
    __shared__ __attribute__((aligned(16))) unsigned short p_lds[64][72];  // [q][key] (wave-private rows)
    __shared__ int sh_idx[16];
    __shared__ int sh_n;

    const int tid = threadIdx.x;
    if (tid == 0) {
        int tmp[16]; int cnt = 0;
        if (partial) {
            const int base = (slot & 1) * 8;
            for (int s = 0; s < 8; ++s) tmp[cnt++] = base + s;
        } else {
            const int cand[8] = { 0, 15, m - 1, m, m + 1,
                                  rnd[m * 3], rnd[m * 3 + 1], rnd[m * 3 + 2] };
            for (int s = 0; s < 8; ++s) {
                bool dup = false;
                for (int t2 = 0; t2 < cnt; ++t2) dup = dup || (tmp[t2] == cand[s]);
                if (!dup) tmp[cnt++] = cand[s];
            }
        }
        sh_n = cnt;
        for (int s = 0; s < cnt; ++s) sh_idx[s] = tmp[s];
    }

    const int w = tid >> 6, lane = tid & 63;
    const int cl = lane & 15;          // "column" lane index
    const int g  = lane >> 4;          // k-group / row-group index
    const size_t bh = (size_t)b * 1024;

    short8 qa0, qa1;
    {
        const bf16* qp = qk + (bh + m * 64 + w * 16 + cl) * LD + h * 64 + g * 8;
        qa0 = *(const short8*)(qp);
        qa1 = *(const short8*)(qp + 32);
    }

    f32x4 o_acc[4] = {};
    f32x4 lp = {};                      // per-lane partial denominator

    const int srow = tid >> 2, sseg = (tid & 3) << 4;   // staging map (K and V)
    const bf16* kbase = qk + 512 + h * 64;
    const bf16* vbase = vt + ((size_t)((b * 8 + h) * 64 + srow) << 10) + sseg;

    __syncthreads();                      // sh_idx ready; all Q reads done
    const int S = sh_n;

    // prefetch tile 0
    short8 kp0, kp1, vp0, vp1;
    {
        const int kb = sh_idx[0];
        const short8* ks8 = (const short8*)(kbase + (bh + kb * 64 + srow) * LD + sseg);
        kp0 = ks8[0]; kp1 = ks8[1];
        const short8* vs8 = (const short8*)(vbase + kb * 64);
        vp0 = vs8[0]; vp1 = vs8[1];
    }

    for (int s = 0; s < S; ++s) {
        // ---- write prefetched K/V regs to LDS (row-major, b128 each) ----
        *(short8*)&k_lds[srow][sseg] = kp0;
        *(short8*)&k_lds[srow][sseg + 8] = kp1;
        *(short8*)&vt_lds[srow][sseg] = vp0;
        *(short8*)&vt_lds[srow][sseg + 8] = vp1;
        __syncthreads();                  // barrier A: stage visible

        // ---- issue next tile's global loads (hidden under compute) ----
        if (s + 1 < S) {
            const int kb = sh_idx[s + 1];
            const short8* ks8 = (const short8*)(kbase + (bh + kb * 64 + srow) * LD + sseg);
            kp0 = ks8[0]; kp1 = ks8[1];
            const short8* vs8 = (const short8*)(vbase + kb * 64);
            vp0 = vs8[0]; vp1 = vs8[1];
        }

        // ---- QK^T: 4 key-tiles x 2 d-steps ----
        f32x4 sc[4];
        __builtin_amdgcn_s_setprio(1);
#pragma unroll
        for (int nt = 0; nt < 4; ++nt) {
            const short8 kb0 = *(const short8*)&k_lds[nt * 16 + cl][g * 8];
            const short8 kb1 = *(const short8*)&k_lds[nt * 16 + cl][32 + g * 8];
            f32x4 acc = {};
            acc = __builtin_amdgcn_mfma_f32_16x16x32_bf16(qa0, kb0, acc, 0, 0, 0);
            acc = __builtin_amdgcn_mfma_f32_16x16x32_bf16(qa1, kb1, acc, 0, 0, 0);
            sc[nt] = acc;
        }
        __builtin_amdgcn_s_setprio(0);

        // ---- p = exp(score), accumulate denominator partials ----
        f32x4 p[4];
#pragma unroll
        for (int nt = 0; nt < 4; ++nt) {
            p[nt].x = __expf(sc[nt].x);
            p[nt].y = __expf(sc[nt].y);
            p[nt].z = __expf(sc[nt].z);
            p[nt].w = __expf(sc[nt].w);
        }
        lp += p[0] + p[1] + p[2] + p[3];

        // ---- P -> bf16 -> LDS (wave-private rows; lgkm-ordered) ----
        {
            const int pr = w * 16 + g * 4;
#pragma unroll
            for (int nt = 0; nt < 4; ++nt) {
                p_lds[pr + 0][nt * 16 + cl] = f2u(p[nt].x);
                p_lds[pr + 1][nt * 16 + cl] = f2u(p[nt].y);
                p_lds[pr + 2][nt * 16 + cl] = f2u(p[nt].z);
                p_lds[pr + 3][nt * 16 + cl] = f2u(p[nt].w);
            }
        }

        // ---- PV: O += P @ V ----
        {
            const short8 pa0 = *(const short8*)&p_lds[w * 16 + cl][g * 8];
            const short8 pa1 = *(const short8*)&p_lds[w * 16 + cl][32 + g * 8];
            __builtin_amdgcn_s_setprio(1);
#pragma unroll
            for (int nt = 0; nt < 4; ++nt) {
                const short8 vb0 = *(const short8*)&vt_lds[nt * 16 + cl][g * 8];
                const short8 vb1 = *(const short8*)&vt_lds[nt * 16 + cl][32 + g * 8];
                o_acc[nt] = __builtin_amdgcn_mfma_f32_16x16x32_bf16(pa0, vb0, o_acc[nt], 0, 0, 0);
                o_acc[nt] = __builtin_amdgcn_mfma_f32_16x16x32_bf16(pa1, vb1, o_acc[nt], 0, 0, 0);
            }
            __builtin_amdgcn_s_setprio(0);
        }
        __syncthreads();       // barrier C: PV/QK reads done before next stage
    }

    // ---- reduce denominator over the 16 cl lanes ----
#pragma unroll
    for (int mask = 1; mask <= 8; mask <<= 1) {
        lp.x += __shfl_xor(lp.x, mask);
        lp.y += __shfl_xor(lp.y, mask);
        lp.z += __shfl_xor(lp.z, mask);
        lp.w += __shfl_xor(lp.w, mask);
    }

    if (partial) {
        // unnormalized partial -> scratch (bf16 o, f32 lp)
        const int ps = bh_idx * 4 + slot;
        unsigned short* op = (unsigned short*)o_part
            + ((size_t)ps * 64 + w * 16 + g * 4) * 64 + cl;
#pragma unroll
        for (int nt = 0; nt < 4; ++nt) {
            op[nt * 16 + 0 * 64] = f2u(o_acc[nt].x);
            op[nt * 16 + 1 * 64] = f2u(o_acc[nt].y);
            op[nt * 16 + 2 * 64] = f2u(o_acc[nt].z);
            op[nt * 16 + 3 * 64] = f2u(o_acc[nt].w);
        }
        if (cl == 0) {
            float* lpp = lp_part + ps * 64 + w * 16 + g * 4;
            lpp[0] = lp.x; lpp[1] = lp.y; lpp[2] = lp.z; lpp[3] = lp.w;
        }
        return;
    }

    f32x4 inv;
    inv.x = 1.0f / lp.x; inv.y = 1.0f / lp.y;
    inv.z = 1.0f / lp.z; inv.w = 1.0f / lp.w;
    const size_t orow = bh + m * 64 + w * 16 + g * 4;
    bf16* ob = qk + orow * LD + h * 64 + cl;
#pragma unroll
    for (int nt = 0; nt < 4; ++nt) {
        const f32x4 ov = o_acc[nt] * inv;
        ((unsigned short*)(ob))[nt * 16] = f2u(ov.x);
        ((unsigned short*)(ob + LD))[nt * 16] = f2u(ov.y);
        ((unsigned short*)(ob + 2 * LD))[nt * 16] = f2u(ov.z);
        ((unsigned short*)(ob + 3 * LD))[nt * 16] = f2u(ov.w);
    }
}

// ---------------- combine the split global-block partials --------------------
// grid (64, 2): (bh_idx, which m: 0->m=0, 1->m=15). 256 thr: q = t>>2,
// 16 d per thread. O = (o0 + o1) / (l0 + l1), write bf16 into qk q-cols.
__global__ __launch_bounds__(256) void attn_combine(
    const bf16* __restrict__ o_part, const float* __restrict__ lp_part,
    bf16* __restrict__ qk)
{
    const int bh_idx = blockIdx.x;
    const int which = blockIdx.y;
    const int b = bh_idx >> 3, h = bh_idx & 7;
    const int m = which ? 15 : 0;
    const int s0 = bh_idx * 4 + which * 2;
    const int t = threadIdx.x;
    const int q = t >> 2, d0 = (t & 3) << 4;

    const float l = lp_part[s0 * 64 + q] + lp_part[(s0 + 1) * 64 + q];
    const float inv = 1.0f / l;
    const bf16* p0 = o_part + ((size_t)s0 * 64 + q) * 64 + d0;
    const bf16* p1 = o_part + ((size_t)(s0 + 1) * 64 + q) * 64 + d0;
    bf16* dst = qk + ((size_t)(b * 1024 + m * 64 + q)) * 1024 + h * 64 + d0;

    const short8 a0 = *(const short8*)p0, a1 = *(const short8*)(p0 + 8);
    const short8 b0 = *(const short8*)p1, b1 = *(const short8*)(p1 + 8);
    short8 r0, r1;
#pragma unroll
    for (int i = 0; i < 8; ++i) {
        r0[i] = (short)f2u((u2f((unsigned short)a0[i]) + u2f((unsigned short)b0[i])) * inv);
        r1[i] = (short)f2u((u2f((unsigned short)a1[i]) + u2f((unsigned short)b1[i])) * inv);
    }
    *(short8*)dst = r0;
    *(short8*)(dst + 8) = r1;
}

// ---------------------------------------------------------------------------
extern "C" void kernel_launch(void* const* d_in, const int* in_sizes, int n_in,
                              void* d_out, int out_size, void* d_ws, size_t ws_size,
                              hipStream_t stream)
{
    (void)in_sizes; (void)n_in; (void)out_size; (void)ws_size;
    const float* inp  = (const float*)d_in[0];
    const float* ln1s = (const float*)d_in[2];
    const float* ln1b = (const float*)d_in[3];
    const float* Wq   = (const float*)d_in[4];
    const float* Wk   = (const float*)d_in[5];
    const float* Wv   = (const float*)d_in[6];
    const float* Wo   = (const float*)d_in[7];
    const float* ln2s = (const float*)d_in[8];
    const float* ln2b = (const float*)d_in[9];
    const float* W1   = (const float*)d_in[10];
    const float* b1   = (const float*)d_in[11];
    const float* W2   = (const float*)d_in[12];
    const float* b2   = (const float*)d_in[13];
    const int*  rnd   = (const int*)d_in[14];
    float* out = (float*)d_out;

    char* ws = (char*)d_ws;
    const size_t MB = 1024 * 1024;
    bf16* WqkvT  = (bf16*)(ws);            // 1.5 MB: [1536][512]
    bf16* WoT    = (bf16*)(ws + 2 * MB);   // 0.5 MB
    bf16* W1T    = (bf16*)(ws + 3 * MB);   // 1 MB: [1024][512]
    bf16* W2T    = (bf16*)(ws + 4 * MB);   // 1 MB: [512][1024]
    bf16* o_part = (bf16*)(ws + 5 * MB);   // 2 MB: [64*4][64][64]
    float* lp_part = (float*)(ws + 7 * MB);// 64 KB: [64*4][64]
    bf16* qk     = (bf16*)(ws + 8 * MB);   // 16 MB: [8192][1024] (q | k)
    bf16* vtb    = (bf16*)(ws + 24 * MB);  // 8 MB: [4096][1024] (V^T per b,h)
    bf16* y      = (bf16*)(ws + 8 * MB);   // alias qk (dead after Wo): LN2 out
    bf16* h1     = (bf16*)(ws + 16 * MB);  // 16 MB: MLP hidden
    bf16* xb     = (bf16*)d_out;           // LN1 out; d_out scratch until Wo GEMM

    prep_kernel<<<6144, 256, 0, stream>>>(Wq, Wk, Wv, Wo, W1, W2,
                                          WqkvT, WoT, W1T, W2T,
                                          inp, ln1s, ln1b, xb);
    mfma_gemm<0, 1, bf16><<<1536, 256, 0, stream>>>(xb, 512, WqkvT, nullptr, nullptr, qk, 1024, 512, vtb, 24);
    attn_kernel<<<1152, 256, 0, stream>>>(qk, vtb, rnd, o_part, lp_part);
    attn_combine<<<dim3(64, 2), 256, 0, stream>>>(o_part, lp_part, qk);
    mfma_gemm<0, 0, float><<<512, 256, 0, stream>>>(qk, 1024, WoT, nullptr, inp, out, 512, 512, nullptr, 8);
    ln_kernel<<<4096, 256, 0, stream>>>(out, ln2s, ln2b, y);
    mfma_gemm<1, 0, bf16><<<1024, 256, 0, stream>>>(y, 512, W1T, b1, nullptr, h1, 1024, 512, nullptr, 16);
    mfma_gemm<0, 0, float><<<512, 256, 0, stream>>>(h1, 1024, W2T, b2, out, out, 512, 1024, nullptr, 8);
}